// Round 1
// baseline (4324.789 us; speedup 1.0000x reference)
//
#include <hip/hip_runtime.h>
#include <stdint.h>

#define HH 8
#define CC 32
#define HC 256   // H*C
#define FF 128
#define NEG 0.2f
#define LNEPS 1e-5f

// ---------- helpers ----------
__device__ inline unsigned bf16r(float f) {           // round-to-nearest-even bf16
  unsigned u = __float_as_uint(f);
  return (u + 0x7fffu + ((u >> 16) & 1u)) >> 16;
}
__device__ inline float bflo(unsigned w) { return __uint_as_float(w << 16); }
__device__ inline float bfhi(unsigned w) { return __uint_as_float(w & 0xffff0000u); }

// order-preserving float<->uint for atomicMax
__device__ inline unsigned enc(float f) {
  unsigned u = __float_as_uint(f);
  return (u & 0x80000000u) ? ~u : (u | 0x80000000u);
}
__device__ inline float dec(unsigned e) {
  unsigned u = (e & 0x80000000u) ? (e ^ 0x80000000u) : ~e;
  return __uint_as_float(u);
}
__device__ inline float leaky(float v) { return v >= 0.f ? v : NEG * v; }

// ---------- K1: xp = x @ W (bf16 out), a_src/a_dst dots ----------
__global__ __launch_bounds__(256) void k1_xform(
    const float* __restrict__ x, const float* __restrict__ W,
    const float* __restrict__ atts, const float* __restrict__ attd,
    unsigned short* __restrict__ xp, float* __restrict__ a_s,
    float* __restrict__ a_d, int n)
{
  int node = blockIdx.x * 256 + threadIdx.x;
  if (node >= n) node = n - 1;            // clamp (duplicate write of same data) keeps CF uniform
  float xr[32];
  const float4* xv = (const float4*)(x + (size_t)node * CC);
#pragma unroll
  for (int i = 0; i < 8; ++i) {
    float4 t = xv[i];
    xr[4*i] = t.x; xr[4*i+1] = t.y; xr[4*i+2] = t.z; xr[4*i+3] = t.w;
  }
  uint4* xpo = (uint4*)(xp + (size_t)node * HC);
  for (int h = 0; h < HH; ++h) {          // runtime loop, uniform
    float ap = 0.f, dp = 0.f;
    for (int c2 = 0; c2 < 4; ++c2) {      // runtime loop, uniform
      int c0 = h * 32 + c2 * 8;
      float acc[8] = {0,0,0,0,0,0,0,0};
#pragma unroll
      for (int k = 0; k < 32; ++k) {
        float xk = xr[k];
        const float* wr = W + k * HC + c0;   // uniform address -> scalar loads
#pragma unroll
        for (int i = 0; i < 8; ++i) acc[i] = fmaf(xk, wr[i], acc[i]);
      }
#pragma unroll
      for (int i = 0; i < 8; ++i) {
        ap = fmaf(acc[i], atts[c0 + i], ap);
        dp = fmaf(acc[i], attd[c0 + i], dp);
      }
      uint4 pk;
      pk.x = bf16r(acc[0]) | (bf16r(acc[1]) << 16);
      pk.y = bf16r(acc[2]) | (bf16r(acc[3]) << 16);
      pk.z = bf16r(acc[4]) | (bf16r(acc[5]) << 16);
      pk.w = bf16r(acc[6]) | (bf16r(acc[7]) << 16);
      xpo[c0 >> 3] = pk;
    }
    a_s[(size_t)node * HH + h] = ap;
    a_d[(size_t)node * HH + h] = dp;
  }
}

// common edge alpha loader
__device__ inline void edge_alpha(const int* __restrict__ ei, int i, int e,
                                  const float* __restrict__ a_s,
                                  const float* __restrict__ a_d,
                                  int& s, int& d, float v[8])
{
  if (i < e) { s = ei[i]; d = ei[e + i]; } else { s = d = i - e; }
  const float4* as = (const float4*)(a_s + (size_t)s * HH);
  const float4* ad = (const float4*)(a_d + (size_t)d * HH);
  float4 s0 = as[0], s1 = as[1], d0 = ad[0], d1 = ad[1];
  v[0] = s0.x + d0.x; v[1] = s0.y + d0.y; v[2] = s0.z + d0.z; v[3] = s0.w + d0.w;
  v[4] = s1.x + d1.x; v[5] = s1.y + d1.y; v[6] = s1.z + d1.z; v[7] = s1.w + d1.w;
}

// ---------- K2: segment max ----------
__global__ __launch_bounds__(256) void k2_max(
    const int* __restrict__ ei, int e, int ep,
    const float* __restrict__ a_s, const float* __restrict__ a_d,
    unsigned* __restrict__ mu)
{
  int i = blockIdx.x * 256 + threadIdx.x;
  if (i >= ep) return;
  int s, d; float v[8];
  edge_alpha(ei, i, e, a_s, a_d, s, d, v);
  unsigned* mrow = mu + (size_t)d * HH;
#pragma unroll
  for (int h = 0; h < 8; ++h) atomicMax(mrow + h, enc(leaky(v[h])));
}

// ---------- K3: segment sum of exp ----------
__global__ __launch_bounds__(256) void k3_sum(
    const int* __restrict__ ei, int e, int ep,
    const float* __restrict__ a_s, const float* __restrict__ a_d,
    const unsigned* __restrict__ mu, float* __restrict__ dn)
{
  int i = blockIdx.x * 256 + threadIdx.x;
  if (i >= ep) return;
  int s, d; float v[8];
  edge_alpha(ei, i, e, a_s, a_d, s, d, v);
  const uint4* mr = (const uint4*)(mu + (size_t)d * HH);
  uint4 m0 = mr[0], m1 = mr[1];
  float* drow = dn + (size_t)d * HH;
  atomicAdd(drow + 0, __expf(leaky(v[0]) - dec(m0.x)));
  atomicAdd(drow + 1, __expf(leaky(v[1]) - dec(m0.y)));
  atomicAdd(drow + 2, __expf(leaky(v[2]) - dec(m0.z)));
  atomicAdd(drow + 3, __expf(leaky(v[3]) - dec(m0.w)));
  atomicAdd(drow + 4, __expf(leaky(v[4]) - dec(m1.x)));
  atomicAdd(drow + 5, __expf(leaky(v[5]) - dec(m1.y)));
  atomicAdd(drow + 6, __expf(leaky(v[6]) - dec(m1.z)));
  atomicAdd(drow + 7, __expf(leaky(v[7]) - dec(m1.w)));
}

// ---------- K4: weighted message aggregation ----------
__global__ __launch_bounds__(256) void k4_agg(
    const int* __restrict__ ei, int e, int ep,
    const float* __restrict__ a_s, const float* __restrict__ a_d,
    const unsigned* __restrict__ mu, const float* __restrict__ dn,
    const unsigned short* __restrict__ xp, float* __restrict__ og)
{
  int i = blockIdx.x * 256 + threadIdx.x;
  if (i >= ep) return;
  int s, d; float v[8];
  edge_alpha(ei, i, e, a_s, a_d, s, d, v);
  const uint4* mr = (const uint4*)(mu + (size_t)d * HH);
  uint4 m0 = mr[0], m1 = mr[1];
  const float4* dr = (const float4*)(dn + (size_t)d * HH);
  float4 dn0 = dr[0], dn1 = dr[1];
  float at[8];
  at[0] = __expf(leaky(v[0]) - dec(m0.x)) / (dn0.x + 1e-16f) * 0.125f;
  at[1] = __expf(leaky(v[1]) - dec(m0.y)) / (dn0.y + 1e-16f) * 0.125f;
  at[2] = __expf(leaky(v[2]) - dec(m0.z)) / (dn0.z + 1e-16f) * 0.125f;
  at[3] = __expf(leaky(v[3]) - dec(m0.w)) / (dn0.w + 1e-16f) * 0.125f;
  at[4] = __expf(leaky(v[4]) - dec(m1.x)) / (dn1.x + 1e-16f) * 0.125f;
  at[5] = __expf(leaky(v[5]) - dec(m1.y)) / (dn1.y + 1e-16f) * 0.125f;
  at[6] = __expf(leaky(v[6]) - dec(m1.z)) / (dn1.z + 1e-16f) * 0.125f;
  at[7] = __expf(leaky(v[7]) - dec(m1.w)) / (dn1.w + 1e-16f) * 0.125f;

  float m32[32];
#pragma unroll
  for (int c = 0; c < 32; ++c) m32[c] = 0.f;
  const uint4* xr = (const uint4*)(xp + (size_t)s * HC);
#pragma unroll
  for (int h = 0; h < 8; ++h) {
    float a = at[h];
#pragma unroll
    for (int q = 0; q < 4; ++q) {
      uint4 w = xr[h * 4 + q];
      m32[8*q+0] = fmaf(a, bflo(w.x), m32[8*q+0]);
      m32[8*q+1] = fmaf(a, bfhi(w.x), m32[8*q+1]);
      m32[8*q+2] = fmaf(a, bflo(w.y), m32[8*q+2]);
      m32[8*q+3] = fmaf(a, bfhi(w.y), m32[8*q+3]);
      m32[8*q+4] = fmaf(a, bflo(w.z), m32[8*q+4]);
      m32[8*q+5] = fmaf(a, bfhi(w.z), m32[8*q+5]);
      m32[8*q+6] = fmaf(a, bflo(w.w), m32[8*q+6]);
      m32[8*q+7] = fmaf(a, bfhi(w.w), m32[8*q+7]);
    }
  }
  float* orow = og + (size_t)d * CC;
#pragma unroll
  for (int c = 0; c < 32; ++c) atomicAdd(orow + c, m32[c]);
}

// ---------- K5: bias + residual + LN1 + FFN + residual + LN2 ----------
__global__ __launch_bounds__(256) void k5_tail(
    const float* __restrict__ og, const float* __restrict__ x,
    const float* __restrict__ bg,
    const float* __restrict__ w1, const float* __restrict__ b1,
    const float* __restrict__ w2, const float* __restrict__ b2,
    const float* __restrict__ g1, const float* __restrict__ be1,
    const float* __restrict__ g2, const float* __restrict__ be2,
    float* __restrict__ out, int n)
{
  int node = blockIdx.x * 256 + threadIdx.x;
  if (node >= n) node = n - 1;
  float hv[32];
  const float4* ov = (const float4*)(og + (size_t)node * CC);
  const float4* xv = (const float4*)(x + (size_t)node * CC);
#pragma unroll
  for (int i = 0; i < 8; ++i) {
    float4 a = ov[i], b = xv[i];
    hv[4*i]   = a.x + b.x + bg[4*i];
    hv[4*i+1] = a.y + b.y + bg[4*i+1];
    hv[4*i+2] = a.z + b.z + bg[4*i+2];
    hv[4*i+3] = a.w + b.w + bg[4*i+3];
  }
  // LN1
  float mu = 0.f;
#pragma unroll
  for (int c = 0; c < 32; ++c) mu += hv[c];
  mu *= (1.f / 32.f);
  float var = 0.f;
#pragma unroll
  for (int c = 0; c < 32; ++c) { float t = hv[c] - mu; var = fmaf(t, t, var); }
  float rs = rsqrtf(var * (1.f / 32.f) + LNEPS);
#pragma unroll
  for (int c = 0; c < 32; ++c) hv[c] = (hv[c] - mu) * rs * g1[c] + be1[c];

  // FFN: ff1 in chunks of 8, immediately folded into ff2 accumulators
  float acc2[32];
#pragma unroll
  for (int c = 0; c < 32; ++c) acc2[c] = 0.f;
  for (int ch = 0; ch < 16; ++ch) {          // runtime loop, uniform
    int c0 = ch * 8;
    float f[8];
#pragma unroll
    for (int i = 0; i < 8; ++i) f[i] = b1[c0 + i];
#pragma unroll
    for (int k = 0; k < 32; ++k) {
      float hk = hv[k];
      const float* wr = w1 + k * FF + c0;    // uniform -> scalar loads
#pragma unroll
      for (int i = 0; i < 8; ++i) f[i] = fmaf(hk, wr[i], f[i]);
    }
#pragma unroll
    for (int i = 0; i < 8; ++i) {
      float fi = fmaxf(f[i], 0.f);
      const float* w2r = w2 + (size_t)(c0 + i) * CC;  // uniform -> scalar loads
#pragma unroll
      for (int c = 0; c < 32; ++c) acc2[c] = fmaf(fi, w2r[c], acc2[c]);
    }
  }
#pragma unroll
  for (int c = 0; c < 32; ++c) acc2[c] += b2[c] + hv[c];
  // LN2
  float mu2 = 0.f;
#pragma unroll
  for (int c = 0; c < 32; ++c) mu2 += acc2[c];
  mu2 *= (1.f / 32.f);
  float var2 = 0.f;
#pragma unroll
  for (int c = 0; c < 32; ++c) { float t = acc2[c] - mu2; var2 = fmaf(t, t, var2); }
  float rs2 = rsqrtf(var2 * (1.f / 32.f) + LNEPS);
  float4* op = (float4*)(out + (size_t)node * CC);
#pragma unroll
  for (int i = 0; i < 8; ++i) {
    float4 o;
    o.x = (acc2[4*i]   - mu2) * rs2 * g2[4*i]   + be2[4*i];
    o.y = (acc2[4*i+1] - mu2) * rs2 * g2[4*i+1] + be2[4*i+1];
    o.z = (acc2[4*i+2] - mu2) * rs2 * g2[4*i+2] + be2[4*i+2];
    o.w = (acc2[4*i+3] - mu2) * rs2 * g2[4*i+3] + be2[4*i+3];
    op[i] = o;
  }
}

// ---------- launch ----------
extern "C" void kernel_launch(void* const* d_in, const int* in_sizes, int n_in,
                              void* d_out, int out_size, void* d_ws, size_t ws_size,
                              hipStream_t stream)
{
  const float* x    = (const float*)d_in[0];
  const int*   ei   = (const int*)d_in[1];
  const float* W    = (const float*)d_in[2];
  const float* atts = (const float*)d_in[3];
  const float* attd = (const float*)d_in[4];
  const float* bg   = (const float*)d_in[5];
  const float* w1   = (const float*)d_in[6];
  const float* b1   = (const float*)d_in[7];
  const float* w2   = (const float*)d_in[8];
  const float* b2   = (const float*)d_in[9];
  const float* g1   = (const float*)d_in[10];
  const float* be1  = (const float*)d_in[11];
  const float* g2   = (const float*)d_in[12];
  const float* be2  = (const float*)d_in[13];

  int n  = in_sizes[0] / CC;
  int e  = in_sizes[1] / 2;
  int ep = e + n;

  uint8_t* ws = (uint8_t*)d_ws;
  size_t o = 0;
  unsigned short* xp = (unsigned short*)(ws + o); o += (size_t)n * HC * 2; o = (o + 255) & ~(size_t)255;
  float*    a_s = (float*)(ws + o);    o += (size_t)n * HH * 4;
  float*    a_d = (float*)(ws + o);    o += (size_t)n * HH * 4;
  size_t zoff = o;
  unsigned* mu  = (unsigned*)(ws + o); o += (size_t)n * HH * 4;
  float*    dn  = (float*)(ws + o);    o += (size_t)n * HH * 4;
  float*    og  = (float*)(ws + o);    o += (size_t)n * CC * 4;

  // zero m (encoded -inf == 0), denom, out accumulator — contiguous region
  hipMemsetAsync(ws + zoff, 0, (size_t)n * (HH + HH + CC) * 4, stream);

  int nb_n = (n + 255) / 256;
  int nb_e = (ep + 255) / 256;

  k1_xform<<<nb_n, 256, 0, stream>>>(x, W, atts, attd, xp, a_s, a_d, n);
  k2_max  <<<nb_e, 256, 0, stream>>>(ei, e, ep, a_s, a_d, mu);
  k3_sum  <<<nb_e, 256, 0, stream>>>(ei, e, ep, a_s, a_d, mu, dn);
  k4_agg  <<<nb_e, 256, 0, stream>>>(ei, e, ep, a_s, a_d, mu, dn, xp, og);
  k5_tail <<<nb_n, 256, 0, stream>>>(og, x, bg, w1, b1, w2, b2, g1, be1, g2, be2,
                                     (float*)d_out, n);
}

// Round 2
// 723.014 us; speedup vs baseline: 5.9816x; 5.9816x over previous
//
#include <hip/hip_runtime.h>
#include <stdint.h>

#define HH 8
#define CC 32
#define HC 256   // H*C
#define FF 128
#define NEG 0.2f
#define LNEPS 1e-5f

// ---------- helpers ----------
__device__ inline unsigned bf16r(float f) {           // round-to-nearest-even bf16
  unsigned u = __float_as_uint(f);
  return (u + 0x7fffu + ((u >> 16) & 1u)) >> 16;
}
__device__ inline float bflo(unsigned w) { return __uint_as_float(w << 16); }
__device__ inline float bfhi(unsigned w) { return __uint_as_float(w & 0xffff0000u); }
__device__ inline float leaky(float v) { return v >= 0.f ? v : NEG * v; }

// ---------- K1: xp = x @ W (bf16 out), a_src/a_dst dots ----------
__global__ __launch_bounds__(256) void k1_xform(
    const float* __restrict__ x, const float* __restrict__ W,
    const float* __restrict__ atts, const float* __restrict__ attd,
    unsigned short* __restrict__ xp, float* __restrict__ a_s,
    float* __restrict__ a_d, int n)
{
  int node = blockIdx.x * 256 + threadIdx.x;
  if (node >= n) node = n - 1;            // clamp keeps CF uniform
  float xr[32];
  const float4* xv = (const float4*)(x + (size_t)node * CC);
#pragma unroll
  for (int i = 0; i < 8; ++i) {
    float4 t = xv[i];
    xr[4*i] = t.x; xr[4*i+1] = t.y; xr[4*i+2] = t.z; xr[4*i+3] = t.w;
  }
  uint4* xpo = (uint4*)(xp + (size_t)node * HC);
  for (int h = 0; h < HH; ++h) {          // runtime loop, uniform
    float ap = 0.f, dp = 0.f;
    for (int c2 = 0; c2 < 4; ++c2) {      // runtime loop, uniform
      int c0 = h * 32 + c2 * 8;
      float acc[8] = {0,0,0,0,0,0,0,0};
#pragma unroll
      for (int k = 0; k < 32; ++k) {
        float xk = xr[k];
        const float* wr = W + k * HC + c0;   // uniform address -> scalar loads
#pragma unroll
        for (int i = 0; i < 8; ++i) acc[i] = fmaf(xk, wr[i], acc[i]);
      }
#pragma unroll
      for (int i = 0; i < 8; ++i) {
        ap = fmaf(acc[i], atts[c0 + i], ap);
        dp = fmaf(acc[i], attd[c0 + i], dp);
      }
      uint4 pk;
      pk.x = bf16r(acc[0]) | (bf16r(acc[1]) << 16);
      pk.y = bf16r(acc[2]) | (bf16r(acc[3]) << 16);
      pk.z = bf16r(acc[4]) | (bf16r(acc[5]) << 16);
      pk.w = bf16r(acc[6]) | (bf16r(acc[7]) << 16);
      xpo[c0 >> 3] = pk;
    }
    a_s[(size_t)node * HH + h] = ap;
    a_d[(size_t)node * HH + h] = dp;
  }
}

// ---------- CSR build: histogram ----------
__global__ __launch_bounds__(256) void khist(const int* __restrict__ ei, int e,
                                             int* __restrict__ deg)
{
  int i = blockIdx.x * 256 + threadIdx.x;
  if (i >= e) return;
  atomicAdd(&deg[ei[e + i]], 1);
}

// ---------- CSR build: exclusive scan (single block, wave-scan) ----------
__global__ __launch_bounds__(1024) void kscan(const int* __restrict__ deg,
                                              int* __restrict__ offs,
                                              int* __restrict__ cursor, int n)
{
  __shared__ int wsum[16];
  int tid = threadIdx.x, lane = tid & 63, wid = tid >> 6;
  int carry = 0;
  for (int base = 0; base < n; base += 1024) {
    int i = base + tid;
    int v = (i < n) ? deg[i] : 0;
    int s = v;
#pragma unroll
    for (int d = 1; d < 64; d <<= 1) { int t = __shfl_up(s, d); if (lane >= d) s += t; }
    if (lane == 63) wsum[wid] = s;
    __syncthreads();
    if (wid == 0) {
      int w = (lane < 16) ? wsum[lane] : 0;
#pragma unroll
      for (int d = 1; d < 16; d <<= 1) { int t = __shfl_up(w, d); if (lane >= d) w += t; }
      if (lane < 16) wsum[lane] = w;
    }
    __syncthreads();
    int woff = (wid > 0) ? wsum[wid - 1] : 0;
    int excl = s - v + woff + carry;
    if (i < n) { offs[i] = excl; cursor[i] = excl; }
    carry += wsum[15];
    __syncthreads();
  }
}

// ---------- CSR build: scatter ----------
__global__ __launch_bounds__(256) void kscatter(const int* __restrict__ ei, int e,
                                                int* __restrict__ cursor,
                                                int* __restrict__ csr)
{
  int i = blockIdx.x * 256 + threadIdx.x;
  if (i >= e) return;
  int s = ei[i], d = ei[e + i];
  int pos = atomicAdd(&cursor[d], 1);
  csr[pos] = s;
}

// ---------- KAGG: wave-per-node fused softmax + aggregation ----------
// lane l: head h = l>>3, channels c0=(l&7)*4 .. +3
__global__ __launch_bounds__(256) void kagg(
    const int* __restrict__ csr, const int* __restrict__ offs,
    const int* __restrict__ deg,
    const float* __restrict__ a_s, const float* __restrict__ a_d,
    const unsigned short* __restrict__ xp, float* __restrict__ og, int n)
{
  int lane = threadIdx.x & 63;
  int node = blockIdx.x * 4 + (threadIdx.x >> 6);
  if (node >= n) return;
  int h = lane >> 3, c0 = (lane & 7) * 4;
  int start = offs[node], dg = deg[node];
  float adh   = a_d[(size_t)node * HH + h];
  float aself = leaky(a_s[(size_t)node * HH + h] + adh);

  // pass 1: online softmax (max + rescaled denom), self-loop seeds it
  float m = aself, dn = 1.f;
  for (int j0 = 0; j0 < dg; j0 += 64) {
    int cnt = min(64, dg - j0);
    int srcj = (j0 + lane < dg) ? csr[start + j0 + lane] : 0;
    for (int j = 0; j < cnt; ++j) {
      int s = __shfl(srcj, j);
      float al = leaky(a_s[(size_t)s * HH + h] + adh);
      float mn = fmaxf(m, al);
      dn = dn * __expf(m - mn) + __expf(al - mn);
      m = mn;
    }
  }
  float inv = 1.f / (dn + 1e-16f);

  // pass 2: weighted aggregation (recompute attn per edge)
  float acc0, acc1, acc2, acc3;
  {
    float at = __expf(aself - m) * inv;
    uint2 wv = *(const uint2*)(xp + (size_t)node * HC + h * 32 + c0);
    acc0 = at * bflo(wv.x); acc1 = at * bfhi(wv.x);
    acc2 = at * bflo(wv.y); acc3 = at * bfhi(wv.y);
  }
  for (int j0 = 0; j0 < dg; j0 += 64) {
    int cnt = min(64, dg - j0);
    int srcj = (j0 + lane < dg) ? csr[start + j0 + lane] : 0;
    for (int j = 0; j < cnt; ++j) {
      int s = __shfl(srcj, j);
      float at = __expf(leaky(a_s[(size_t)s * HH + h] + adh) - m) * inv;
      uint2 wv = *(const uint2*)(xp + (size_t)s * HC + h * 32 + c0);
      acc0 = fmaf(at, bflo(wv.x), acc0); acc1 = fmaf(at, bfhi(wv.x), acc1);
      acc2 = fmaf(at, bflo(wv.y), acc2); acc3 = fmaf(at, bfhi(wv.y), acc3);
    }
  }

  // head mean: reduce across the 8 lanes sharing (lane&7)
#pragma unroll
  for (int mask = 8; mask < 64; mask <<= 1) {
    acc0 += __shfl_xor(acc0, mask);
    acc1 += __shfl_xor(acc1, mask);
    acc2 += __shfl_xor(acc2, mask);
    acc3 += __shfl_xor(acc3, mask);
  }
  if (lane < 8) {
    float4 o = make_float4(acc0 * 0.125f, acc1 * 0.125f,
                           acc2 * 0.125f, acc3 * 0.125f);
    *(float4*)(og + (size_t)node * CC + lane * 4) = o;
  }
}

// ---------- K5: bias + residual + LN1 + FFN + residual + LN2 ----------
__global__ __launch_bounds__(256) void k5_tail(
    const float* __restrict__ og, const float* __restrict__ x,
    const float* __restrict__ bg,
    const float* __restrict__ w1, const float* __restrict__ b1,
    const float* __restrict__ w2, const float* __restrict__ b2,
    const float* __restrict__ g1, const float* __restrict__ be1,
    const float* __restrict__ g2, const float* __restrict__ be2,
    float* __restrict__ out, int n)
{
  int node = blockIdx.x * 256 + threadIdx.x;
  if (node >= n) node = n - 1;
  float hv[32];
  const float4* ov = (const float4*)(og + (size_t)node * CC);
  const float4* xv = (const float4*)(x + (size_t)node * CC);
#pragma unroll
  for (int i = 0; i < 8; ++i) {
    float4 a = ov[i], b = xv[i];
    hv[4*i]   = a.x + b.x + bg[4*i];
    hv[4*i+1] = a.y + b.y + bg[4*i+1];
    hv[4*i+2] = a.z + b.z + bg[4*i+2];
    hv[4*i+3] = a.w + b.w + bg[4*i+3];
  }
  float mu = 0.f;
#pragma unroll
  for (int c = 0; c < 32; ++c) mu += hv[c];
  mu *= (1.f / 32.f);
  float var = 0.f;
#pragma unroll
  for (int c = 0; c < 32; ++c) { float t = hv[c] - mu; var = fmaf(t, t, var); }
  float rs = rsqrtf(var * (1.f / 32.f) + LNEPS);
#pragma unroll
  for (int c = 0; c < 32; ++c) hv[c] = (hv[c] - mu) * rs * g1[c] + be1[c];

  float acc2[32];
#pragma unroll
  for (int c = 0; c < 32; ++c) acc2[c] = 0.f;
  for (int ch = 0; ch < 16; ++ch) {          // runtime loop, uniform
    int c0 = ch * 8;
    float f[8];
#pragma unroll
    for (int i = 0; i < 8; ++i) f[i] = b1[c0 + i];
#pragma unroll
    for (int k = 0; k < 32; ++k) {
      float hk = hv[k];
      const float* wr = w1 + k * FF + c0;    // uniform -> scalar loads
#pragma unroll
      for (int i = 0; i < 8; ++i) f[i] = fmaf(hk, wr[i], f[i]);
    }
#pragma unroll
    for (int i = 0; i < 8; ++i) {
      float fi = fmaxf(f[i], 0.f);
      const float* w2r = w2 + (size_t)(c0 + i) * CC;  // uniform -> scalar loads
#pragma unroll
      for (int c = 0; c < 32; ++c) acc2[c] = fmaf(fi, w2r[c], acc2[c]);
    }
  }
#pragma unroll
  for (int c = 0; c < 32; ++c) acc2[c] += b2[c] + hv[c];
  float mu2 = 0.f;
#pragma unroll
  for (int c = 0; c < 32; ++c) mu2 += acc2[c];
  mu2 *= (1.f / 32.f);
  float var2 = 0.f;
#pragma unroll
  for (int c = 0; c < 32; ++c) { float t = acc2[c] - mu2; var2 = fmaf(t, t, var2); }
  float rs2 = rsqrtf(var2 * (1.f / 32.f) + LNEPS);
  float4* op = (float4*)(out + (size_t)node * CC);
#pragma unroll
  for (int i = 0; i < 8; ++i) {
    float4 o;
    o.x = (acc2[4*i]   - mu2) * rs2 * g2[4*i]   + be2[4*i];
    o.y = (acc2[4*i+1] - mu2) * rs2 * g2[4*i+1] + be2[4*i+1];
    o.z = (acc2[4*i+2] - mu2) * rs2 * g2[4*i+2] + be2[4*i+2];
    o.w = (acc2[4*i+3] - mu2) * rs2 * g2[4*i+3] + be2[4*i+3];
    op[i] = o;
  }
}

// ---------- launch ----------
extern "C" void kernel_launch(void* const* d_in, const int* in_sizes, int n_in,
                              void* d_out, int out_size, void* d_ws, size_t ws_size,
                              hipStream_t stream)
{
  const float* x    = (const float*)d_in[0];
  const int*   ei   = (const int*)d_in[1];
  const float* W    = (const float*)d_in[2];
  const float* atts = (const float*)d_in[3];
  const float* attd = (const float*)d_in[4];
  const float* bg   = (const float*)d_in[5];
  const float* w1   = (const float*)d_in[6];
  const float* b1   = (const float*)d_in[7];
  const float* w2   = (const float*)d_in[8];
  const float* b2   = (const float*)d_in[9];
  const float* g1   = (const float*)d_in[10];
  const float* be1  = (const float*)d_in[11];
  const float* g2   = (const float*)d_in[12];
  const float* be2  = (const float*)d_in[13];

  int n = in_sizes[0] / CC;
  int e = in_sizes[1] / 2;

  uint8_t* ws = (uint8_t*)d_ws;
  size_t o = 0;
  unsigned short* xp = (unsigned short*)(ws + o); o += (size_t)n * HC * 2; o = (o + 255) & ~(size_t)255;
  float* a_s = (float*)(ws + o); o += (size_t)n * HH * 4;
  float* a_d = (float*)(ws + o); o += (size_t)n * HH * 4;
  float* og  = (float*)(ws + o); o += (size_t)n * CC * 4;
  int* deg    = (int*)(ws + o); o += (size_t)n * 4;
  int* offs   = (int*)(ws + o); o += (size_t)n * 4;
  int* cursor = (int*)(ws + o); o += (size_t)n * 4;
  int* csr    = (int*)(ws + o); o += (size_t)e * 4;

  hipMemsetAsync(deg, 0, (size_t)n * 4, stream);

  int nb_n = (n + 255) / 256;
  int nb_e = (e + 255) / 256;

  k1_xform<<<nb_n, 256, 0, stream>>>(x, W, atts, attd, xp, a_s, a_d, n);
  khist   <<<nb_e, 256, 0, stream>>>(ei, e, deg);
  kscan   <<<1, 1024, 0, stream>>>(deg, offs, cursor, n);
  kscatter<<<nb_e, 256, 0, stream>>>(ei, e, cursor, csr);
  kagg    <<<(n + 3) / 4, 256, 0, stream>>>(csr, offs, deg, a_s, a_d, xp, og, n);
  k5_tail <<<nb_n, 256, 0, stream>>>(og, x, bg, w1, b1, w2, b2, g1, be1, g2, be2,
                                     (float*)d_out, n);
}

// Round 3
// 528.421 us; speedup vs baseline: 8.1844x; 1.3683x over previous
//
#include <hip/hip_runtime.h>
#include <stdint.h>

#define HH 8
#define CC 32
#define HC 256   // H*C
#define FF 128
#define NEG 0.2f
#define LNEPS 1e-5f

// ---------- helpers ----------
__device__ inline unsigned bf16r(float f) {           // round-to-nearest-even bf16
  unsigned u = __float_as_uint(f);
  return (u + 0x7fffu + ((u >> 16) & 1u)) >> 16;
}
__device__ inline float bflo(unsigned w) { return __uint_as_float(w << 16); }
__device__ inline float bfhi(unsigned w) { return __uint_as_float(w & 0xffff0000u); }
__device__ inline float leaky(float v) { return v >= 0.f ? v : NEG * v; }

// ---------- K1H: fused xp = x@W + a_src/a_dst dots + degree histogram ----------
__global__ __launch_bounds__(256) void k1h(
    const float* __restrict__ x, const float* __restrict__ W,
    const float* __restrict__ atts, const float* __restrict__ attd,
    const int* __restrict__ ei,
    unsigned short* __restrict__ xp, float* __restrict__ a_s,
    float* __restrict__ a_d, int* __restrict__ deg,
    int n, int e, int nb_n)
{
  if ((int)blockIdx.x >= nb_n) {
    // histogram role: 4 edges per thread
    int i = ((int)blockIdx.x - nb_n) * 1024 + (int)threadIdx.x * 4;
    if (i >= e) return;
    const int* dst = ei + e;
    if (i + 3 < e) {
      int4 d4 = *(const int4*)(dst + i);
      atomicAdd(&deg[d4.x], 1); atomicAdd(&deg[d4.y], 1);
      atomicAdd(&deg[d4.z], 1); atomicAdd(&deg[d4.w], 1);
    } else {
      for (int k = 0; k < 4 && i + k < e; ++k) atomicAdd(&deg[dst[i + k]], 1);
    }
    return;
  }
  int node = (int)blockIdx.x * 256 + (int)threadIdx.x;
  if (node >= n) node = n - 1;            // clamp keeps CF uniform
  float xr[32];
  const float4* xv = (const float4*)(x + (size_t)node * CC);
#pragma unroll
  for (int i = 0; i < 8; ++i) {
    float4 t = xv[i];
    xr[4*i] = t.x; xr[4*i+1] = t.y; xr[4*i+2] = t.z; xr[4*i+3] = t.w;
  }
  uint4* xpo = (uint4*)(xp + (size_t)node * HC);
  for (int h = 0; h < HH; ++h) {          // runtime loop, uniform
    float ap = 0.f, dp = 0.f;
    for (int c2 = 0; c2 < 4; ++c2) {      // runtime loop, uniform
      int c0 = h * 32 + c2 * 8;
      float acc[8] = {0,0,0,0,0,0,0,0};
#pragma unroll
      for (int k = 0; k < 32; ++k) {
        float xk = xr[k];
        const float* wr = W + k * HC + c0;   // uniform address -> scalar loads
#pragma unroll
        for (int i = 0; i < 8; ++i) acc[i] = fmaf(xk, wr[i], acc[i]);
      }
#pragma unroll
      for (int i = 0; i < 8; ++i) {
        ap = fmaf(acc[i], atts[c0 + i], ap);
        dp = fmaf(acc[i], attd[c0 + i], dp);
      }
      uint4 pk;
      pk.x = bf16r(acc[0]) | (bf16r(acc[1]) << 16);
      pk.y = bf16r(acc[2]) | (bf16r(acc[3]) << 16);
      pk.z = bf16r(acc[4]) | (bf16r(acc[5]) << 16);
      pk.w = bf16r(acc[6]) | (bf16r(acc[7]) << 16);
      xpo[c0 >> 3] = pk;
    }
    a_s[(size_t)node * HH + h] = ap;
    a_d[(size_t)node * HH + h] = dp;
  }
}

// ---------- scan phase A: per-1024-block sums ----------
__global__ __launch_bounds__(256) void kscanA(const int* __restrict__ deg,
                                              int* __restrict__ bsum, int n)
{
  __shared__ int ws[4];
  int t = threadIdx.x;
  int i = (int)blockIdx.x * 1024 + t * 4;
  int4 v = make_int4(0, 0, 0, 0);
  if (i + 3 < n) v = *(const int4*)(deg + i);
  else {
    if (i     < n) v.x = deg[i];
    if (i + 1 < n) v.y = deg[i + 1];
    if (i + 2 < n) v.z = deg[i + 2];
    if (i + 3 < n) v.w = deg[i + 3];
  }
  int s = v.x + v.y + v.z + v.w;
#pragma unroll
  for (int mask = 1; mask < 64; mask <<= 1) s += __shfl_xor(s, mask);
  if ((t & 63) == 0) ws[t >> 6] = s;
  __syncthreads();
  if (t == 0) bsum[blockIdx.x] = ws[0] + ws[1] + ws[2] + ws[3];
}

// ---------- scan phase B: exclusive scan of block sums (<=1024 blocks) ----------
__global__ __launch_bounds__(1024) void kscanB(int* __restrict__ bsum, int nb)
{
  __shared__ int wsum[16];
  int t = threadIdx.x, lane = t & 63, wid = t >> 6;
  int v = (t < nb) ? bsum[t] : 0;
  int s = v;
#pragma unroll
  for (int d = 1; d < 64; d <<= 1) { int tt = __shfl_up(s, d); if (lane >= d) s += tt; }
  if (lane == 63) wsum[wid] = s;
  __syncthreads();
  if (wid == 0) {
    int w = (lane < 16) ? wsum[lane] : 0;
#pragma unroll
    for (int d = 1; d < 16; d <<= 1) { int tt = __shfl_up(w, d); if (lane >= d) w += tt; }
    if (lane < 16) wsum[lane] = w;
  }
  __syncthreads();
  int excl = s - v + ((wid > 0) ? wsum[wid - 1] : 0);
  if (t < nb) bsum[t] = excl;
}

// ---------- scan phase C: local rescan + global offset -> offs, cursor ----------
__global__ __launch_bounds__(256) void kscanC(const int* __restrict__ deg,
                                              const int* __restrict__ bsum,
                                              int* __restrict__ offs,
                                              int* __restrict__ cursor, int n)
{
  __shared__ int ws[4];
  int t = threadIdx.x, lane = t & 63, wid = t >> 6;
  int i = (int)blockIdx.x * 1024 + t * 4;
  int4 v = make_int4(0, 0, 0, 0);
  if (i + 3 < n) v = *(const int4*)(deg + i);
  else {
    if (i     < n) v.x = deg[i];
    if (i + 1 < n) v.y = deg[i + 1];
    if (i + 2 < n) v.z = deg[i + 2];
    if (i + 3 < n) v.w = deg[i + 3];
  }
  int tsum = v.x + v.y + v.z + v.w;
  int s = tsum;
#pragma unroll
  for (int d = 1; d < 64; d <<= 1) { int tt = __shfl_up(s, d); if (lane >= d) s += tt; }
  if (lane == 63) ws[wid] = s;
  __syncthreads();
  if (t == 0) {
    int a = ws[0]; ws[0] = 0;
    int b = ws[1]; ws[1] = a; a += b;
    int c = ws[2]; ws[2] = a; a += c;
    ws[3] = a;
  }
  __syncthreads();
  int base = bsum[blockIdx.x] + ws[wid] + (s - tsum);
  if (i     < n) { offs[i]     = base; cursor[i]     = base; } base += v.x;
  if (i + 1 < n) { offs[i + 1] = base; cursor[i + 1] = base; } base += v.y;
  if (i + 2 < n) { offs[i + 2] = base; cursor[i + 2] = base; } base += v.z;
  if (i + 3 < n) { offs[i + 3] = base; cursor[i + 3] = base; }
}

// ---------- CSR scatter ----------
__global__ __launch_bounds__(256) void kscatter(const int* __restrict__ ei, int e,
                                                int* __restrict__ cursor,
                                                int* __restrict__ csr)
{
  int i = (int)blockIdx.x * 1024 + (int)threadIdx.x * 4;
  if (i >= e) return;
  if (i + 3 < e) {
    int4 s4 = *(const int4*)(ei + i);
    int4 d4 = *(const int4*)(ei + e + i);
    csr[atomicAdd(&cursor[d4.x], 1)] = s4.x;
    csr[atomicAdd(&cursor[d4.y], 1)] = s4.y;
    csr[atomicAdd(&cursor[d4.z], 1)] = s4.z;
    csr[atomicAdd(&cursor[d4.w], 1)] = s4.w;
  } else {
    for (int k = 0; k < 4 && i + k < e; ++k) {
      int s = ei[i + k], d = ei[e + i + k];
      csr[atomicAdd(&cursor[d], 1)] = s;
    }
  }
}

// ---------- KAGG: wave-per-node, chunk-of-8 parallel online softmax + agg ----------
// phase-A layout: eg = lane>>3 (edge in chunk), ha = lane&7 (head)
// phase-B layout: hb = lane>>3 (head),          c0 = (lane&7)*4 (channels)
__global__ __launch_bounds__(256) void kagg(
    const int* __restrict__ csr, const int* __restrict__ offs,
    const int* __restrict__ deg,
    const float* __restrict__ a_s, const float* __restrict__ a_d,
    const unsigned short* __restrict__ xp, float* __restrict__ og, int n)
{
  int lane = threadIdx.x & 63;
  int node = (int)blockIdx.x * 4 + (threadIdx.x >> 6);
  if (node >= n) return;
  int eg = lane >> 3, ha = lane & 7;
  int hb = eg;                       // head in B layout
  int boff = hb * 32 + (lane & 7) * 4;

  int start = offs[node];
  int dg = deg[node];
  float ad_a  = a_d[(size_t)node * HH + ha];
  float aself = leaky(a_s[(size_t)node * HH + ha] + ad_a);
  float m = aself, dn = 1.f;
  float acc0 = 0.f, acc1 = 0.f, acc2 = 0.f, acc3 = 0.f;

  for (int j0 = 0; j0 < dg; j0 += 8) {
    int rem = dg - j0;
    int cnt = rem < 8 ? rem : 8;
    int idx = j0 + eg;
    int srcl = 0; float al = -3.0e38f;
    if (idx < dg) {
      srcl = csr[start + idx];
      al = leaky(a_s[(size_t)srcl * HH + ha] + ad_a);
    }
    // chunk max over edge dim
    float cm = fmaxf(al, __shfl_xor(al, 8));
    cm = fmaxf(cm, __shfl_xor(cm, 16));
    cm = fmaxf(cm, __shfl_xor(cm, 32));
    float mn = fmaxf(m, cm);
    float scale = __expf(m - mn);
    m = mn;
    float p = (idx < dg) ? __expf(al - m) : 0.f;
    float ps = p + __shfl_xor(p, 8);
    ps += __shfl_xor(ps, 16);
    ps += __shfl_xor(ps, 32);
    dn = dn * scale + ps;
    // rescale accumulators (B layout): scale for head hb lives at lane hb
    float sb = __shfl(scale, hb);
    acc0 *= sb; acc1 *= sb; acc2 *= sb; acc3 *= sb;
    if (cnt == 8) {
#pragma unroll
      for (int j = 0; j < 8; ++j) {
        float at = __shfl(p, (j << 3) + hb);
        int s = __shfl(srcl, j << 3);
        uint2 wv = *(const uint2*)(xp + ((size_t)s << 8) + boff);
        acc0 = fmaf(at, bflo(wv.x), acc0);
        acc1 = fmaf(at, bfhi(wv.x), acc1);
        acc2 = fmaf(at, bflo(wv.y), acc2);
        acc3 = fmaf(at, bfhi(wv.y), acc3);
      }
    } else {
      for (int j = 0; j < cnt; ++j) {
        float at = __shfl(p, (j << 3) + hb);
        int s = __shfl(srcl, j << 3);
        uint2 wv = *(const uint2*)(xp + ((size_t)s << 8) + boff);
        acc0 = fmaf(at, bflo(wv.x), acc0);
        acc1 = fmaf(at, bfhi(wv.x), acc1);
        acc2 = fmaf(at, bflo(wv.y), acc2);
        acc3 = fmaf(at, bfhi(wv.y), acc3);
      }
    }
  }
  // self loop (seeded m/dn with it; add its message now)
  float sw_a = __expf(aself - m);
  float sw  = __shfl(sw_a, hb);
  float dnb = __shfl(dn, hb);
  {
    uint2 wv = *(const uint2*)(xp + ((size_t)node << 8) + boff);
    acc0 = fmaf(sw, bflo(wv.x), acc0);
    acc1 = fmaf(sw, bfhi(wv.x), acc1);
    acc2 = fmaf(sw, bflo(wv.y), acc2);
    acc3 = fmaf(sw, bfhi(wv.y), acc3);
  }
  float inv = 0.125f / (dnb + 1e-16f);
  acc0 *= inv; acc1 *= inv; acc2 *= inv; acc3 *= inv;
  // head mean across hb
#pragma unroll
  for (int mask = 8; mask < 64; mask <<= 1) {
    acc0 += __shfl_xor(acc0, mask);
    acc1 += __shfl_xor(acc1, mask);
    acc2 += __shfl_xor(acc2, mask);
    acc3 += __shfl_xor(acc3, mask);
  }
  if (lane < 8) {
    *(float4*)(og + (size_t)node * CC + lane * 4) =
      make_float4(acc0, acc1, acc2, acc3);
  }
}

// ---------- K5: bias + residual + LN1 + FFN + residual + LN2 ----------
__global__ __launch_bounds__(256) void k5_tail(
    const float* __restrict__ og, const float* __restrict__ x,
    const float* __restrict__ bg,
    const float* __restrict__ w1, const float* __restrict__ b1,
    const float* __restrict__ w2, const float* __restrict__ b2,
    const float* __restrict__ g1, const float* __restrict__ be1,
    const float* __restrict__ g2, const float* __restrict__ be2,
    float* __restrict__ out, int n)
{
  int node = (int)blockIdx.x * 256 + (int)threadIdx.x;
  if (node >= n) node = n - 1;
  float hv[32];
  const float4* ov = (const float4*)(og + (size_t)node * CC);
  const float4* xv = (const float4*)(x + (size_t)node * CC);
#pragma unroll
  for (int i = 0; i < 8; ++i) {
    float4 a = ov[i], b = xv[i];
    hv[4*i]   = a.x + b.x + bg[4*i];
    hv[4*i+1] = a.y + b.y + bg[4*i+1];
    hv[4*i+2] = a.z + b.z + bg[4*i+2];
    hv[4*i+3] = a.w + b.w + bg[4*i+3];
  }
  float mu = 0.f;
#pragma unroll
  for (int c = 0; c < 32; ++c) mu += hv[c];
  mu *= (1.f / 32.f);
  float var = 0.f;
#pragma unroll
  for (int c = 0; c < 32; ++c) { float t = hv[c] - mu; var = fmaf(t, t, var); }
  float rs = rsqrtf(var * (1.f / 32.f) + LNEPS);
#pragma unroll
  for (int c = 0; c < 32; ++c) hv[c] = (hv[c] - mu) * rs * g1[c] + be1[c];

  float acc2[32];
#pragma unroll
  for (int c = 0; c < 32; ++c) acc2[c] = 0.f;
  for (int ch = 0; ch < 16; ++ch) {          // runtime loop, uniform
    int c0 = ch * 8;
    float f[8];
#pragma unroll
    for (int i = 0; i < 8; ++i) f[i] = b1[c0 + i];
#pragma unroll
    for (int k = 0; k < 32; ++k) {
      float hk = hv[k];
      const float* wr = w1 + k * FF + c0;    // uniform -> scalar loads
#pragma unroll
      for (int i = 0; i < 8; ++i) f[i] = fmaf(hk, wr[i], f[i]);
    }
#pragma unroll
    for (int i = 0; i < 8; ++i) {
      float fi = fmaxf(f[i], 0.f);
      const float* w2r = w2 + (size_t)(c0 + i) * CC;  // uniform -> scalar loads
#pragma unroll
      for (int c = 0; c < 32; ++c) acc2[c] = fmaf(fi, w2r[c], acc2[c]);
    }
  }
#pragma unroll
  for (int c = 0; c < 32; ++c) acc2[c] += b2[c] + hv[c];
  float mu2 = 0.f;
#pragma unroll
  for (int c = 0; c < 32; ++c) mu2 += acc2[c];
  mu2 *= (1.f / 32.f);
  float var2 = 0.f;
#pragma unroll
  for (int c = 0; c < 32; ++c) { float t = acc2[c] - mu2; var2 = fmaf(t, t, var2); }
  float rs2 = rsqrtf(var2 * (1.f / 32.f) + LNEPS);
  float4* op = (float4*)(out + (size_t)node * CC);
#pragma unroll
  for (int i = 0; i < 8; ++i) {
    float4 o;
    o.x = (acc2[4*i]   - mu2) * rs2 * g2[4*i]   + be2[4*i];
    o.y = (acc2[4*i+1] - mu2) * rs2 * g2[4*i+1] + be2[4*i+1];
    o.z = (acc2[4*i+2] - mu2) * rs2 * g2[4*i+2] + be2[4*i+2];
    o.w = (acc2[4*i+3] - mu2) * rs2 * g2[4*i+3] + be2[4*i+3];
    op[i] = o;
  }
}

// ---------- launch ----------
extern "C" void kernel_launch(void* const* d_in, const int* in_sizes, int n_in,
                              void* d_out, int out_size, void* d_ws, size_t ws_size,
                              hipStream_t stream)
{
  const float* x    = (const float*)d_in[0];
  const int*   ei   = (const int*)d_in[1];
  const float* W    = (const float*)d_in[2];
  const float* atts = (const float*)d_in[3];
  const float* attd = (const float*)d_in[4];
  const float* bg   = (const float*)d_in[5];
  const float* w1   = (const float*)d_in[6];
  const float* b1   = (const float*)d_in[7];
  const float* w2   = (const float*)d_in[8];
  const float* b2   = (const float*)d_in[9];
  const float* g1   = (const float*)d_in[10];
  const float* be1  = (const float*)d_in[11];
  const float* g2   = (const float*)d_in[12];
  const float* be2  = (const float*)d_in[13];

  int n = in_sizes[0] / CC;
  int e = in_sizes[1] / 2;

  uint8_t* ws = (uint8_t*)d_ws;
  size_t o = 0;
  unsigned short* xp = (unsigned short*)(ws + o); o += (size_t)n * HC * 2; o = (o + 255) & ~(size_t)255;
  float* a_s = (float*)(ws + o); o += (size_t)n * HH * 4;
  float* a_d = (float*)(ws + o); o += (size_t)n * HH * 4;
  float* og  = (float*)(ws + o); o += (size_t)n * CC * 4;
  int* deg    = (int*)(ws + o); o += (size_t)n * 4;
  int* offs   = (int*)(ws + o); o += (size_t)n * 4;
  int* cursor = (int*)(ws + o); o += (size_t)n * 4;
  int* csr    = (int*)(ws + o); o += (size_t)e * 4;
  int* bsum   = (int*)(ws + o); o += 4096;

  hipMemsetAsync(deg, 0, (size_t)n * 4, stream);

  int nb_n  = (n + 255) / 256;
  int nb_e4 = (e + 1023) / 1024;
  int nb_s  = (n + 1023) / 1024;     // scan blocks (must be <= 1024)

  k1h     <<<nb_n + nb_e4, 256, 0, stream>>>(x, W, atts, attd, ei, xp, a_s, a_d,
                                             deg, n, e, nb_n);
  kscanA  <<<nb_s, 256, 0, stream>>>(deg, bsum, n);
  kscanB  <<<1, 1024, 0, stream>>>(bsum, nb_s);
  kscanC  <<<nb_s, 256, 0, stream>>>(deg, bsum, offs, cursor, n);
  kscatter<<<nb_e4, 256, 0, stream>>>(ei, e, cursor, csr);
  kagg    <<<(n + 3) / 4, 256, 0, stream>>>(csr, offs, deg, a_s, a_d, xp, og, n);
  k5_tail <<<nb_n, 256, 0, stream>>>(og, x, bg, w1, b1, w2, b2, g1, be1, g2, be2,
                                     (float*)d_out, n);
}

// Round 4
// 394.560 us; speedup vs baseline: 10.9610x; 1.3393x over previous
//
#include <hip/hip_runtime.h>
#include <stdint.h>

#define HH 8
#define CC 32
#define HC 256   // H*C
#define FF 128
#define NEG 0.2f
#define LNEPS 1e-5f

typedef __attribute__((ext_vector_type(8))) short bf16x8;
typedef __attribute__((ext_vector_type(4))) float f32x4;
typedef unsigned short u16;

// ---------- helpers ----------
__device__ inline unsigned bf16r(float f) {           // round-to-nearest-even bf16
  unsigned u = __float_as_uint(f);
  return (u + 0x7fffu + ((u >> 16) & 1u)) >> 16;
}
__device__ inline float bflo(unsigned w) { return __uint_as_float(w << 16); }
__device__ inline float bfhi(unsigned w) { return __uint_as_float(w & 0xffff0000u); }
__device__ inline float leaky(float v) { return v >= 0.f ? v : NEG * v; }

// ---------- KLAYOUT: repack weights into MFMA B-fragment layout (bf16) ----------
// B-frag (16x16x32): lane l supplies B[8*(l>>4)+j][l&15], j=0..7 contiguous.
__global__ __launch_bounds__(256) void klayout(
    const float* __restrict__ W, const float* __restrict__ atts,
    const float* __restrict__ attd, const float* __restrict__ w1,
    const float* __restrict__ w2,
    u16* __restrict__ Wb, u16* __restrict__ Zb,
    u16* __restrict__ V1b, u16* __restrict__ V2b)
{
  int t = threadIdx.x;
  for (int i = t; i < 16 * 512; i += 256) {        // Wb: W_gat [32,256]
    int j = i & 7, l = (i >> 3) & 63, nb = i >> 9;
    int k = 8 * (l >> 4) + j, c = 16 * nb + (l & 15);
    Wb[i] = (u16)bf16r(W[k * HC + c]);
  }
  for (int i = t; i < 8 * 512; i += 256) {         // Zb: [256,16] = [atts|attd] blockdiag
    int j = i & 7, l = (i >> 3) & 63, kb = i >> 9;
    int k = 32 * kb + 8 * (l >> 4) + j;            // channel 0..255
    int tc = l & 15;
    float v = 0.f;
    if (tc < 8)  { if ((k >> 5) == tc)     v = atts[tc * 32 + (k & 31)]; }
    else         { if ((k >> 5) == tc - 8) v = attd[(tc - 8) * 32 + (k & 31)]; }
    Zb[i] = (u16)bf16r(v);
  }
  for (int i = t; i < 8 * 512; i += 256) {         // V1b: w1 [32,128]
    int j = i & 7, l = (i >> 3) & 63, nb = i >> 9;
    int k = 8 * (l >> 4) + j, c = 16 * nb + (l & 15);
    V1b[i] = (u16)bf16r(w1[k * FF + c]);
  }
  for (int i = t; i < 8 * 512; i += 256) {         // V2b: w2 [128,32]
    int j = i & 7, l = (i >> 3) & 63, kn = i >> 9;
    int kb = kn >> 1, nb2 = kn & 1;
    int k = 32 * kb + 8 * (l >> 4) + j, c = 16 * nb2 + (l & 15);
    V2b[i] = (u16)bf16r(w2[k * CC + c]);
  }
}

// ---------- K1M: MFMA xp = x@W (bf16) + a_src/a_dst via Z-mfma + fused histogram ----------
__global__ __launch_bounds__(256) void k1m(
    const float* __restrict__ x, const u16* __restrict__ Wb,
    const u16* __restrict__ Zb, const int* __restrict__ ei,
    u16* __restrict__ xp, float* __restrict__ a_s, float* __restrict__ a_d,
    int* __restrict__ deg, int n, int e, int nbc)
{
  if ((int)blockIdx.x >= nbc) {                    // histogram role
    int i = ((int)blockIdx.x - nbc) * 1024 + (int)threadIdx.x * 4;
    if (i >= e) return;
    const int* dst = ei + e;
    if (i + 3 < e) {
      int4 d4 = *(const int4*)(dst + i);
      atomicAdd(&deg[d4.x], 1); atomicAdd(&deg[d4.y], 1);
      atomicAdd(&deg[d4.z], 1); atomicAdd(&deg[d4.w], 1);
    } else {
      for (int k = 0; k < 4 && i + k < e; ++k) atomicAdd(&deg[dst[i + k]], 1);
    }
    return;
  }
  __shared__ u16 lt[4][16 * 264];                  // per-wave [16 rows][264 halfs]
  int wid = threadIdx.x >> 6, lane = threadIdx.x & 63;
  int q = lane & 15, g = lane >> 4;
  long node0 = (long)((int)blockIdx.x * 4 + wid) * 16;
  if (node0 + 16 > n) node0 = n - 16;              // overlap tail: duplicate identical writes
  u16* L = lt[wid];

  // A-frag: x[node0+q][8g..8g+7] -> bf16
  const float* xr = x + (node0 + q) * CC + 8 * g;
  float4 xa = *(const float4*)xr, xb = *(const float4*)(xr + 4);
  bf16x8 af;
  af[0] = (short)bf16r(xa.x); af[1] = (short)bf16r(xa.y);
  af[2] = (short)bf16r(xa.z); af[3] = (short)bf16r(xa.w);
  af[4] = (short)bf16r(xb.x); af[5] = (short)bf16r(xb.y);
  af[6] = (short)bf16r(xb.z); af[7] = (short)bf16r(xb.w);

#pragma unroll
  for (int nb = 0; nb < 16; ++nb) {
    bf16x8 bf = *(const bf16x8*)(Wb + nb * 512 + lane * 8);
    f32x4 acc = {0.f, 0.f, 0.f, 0.f};
    acc = __builtin_amdgcn_mfma_f32_16x16x32_bf16(af, bf, acc, 0, 0, 0);
    int col = 16 * nb + q;
#pragma unroll
    for (int r = 0; r < 4; ++r)
      L[(4 * g + r) * 264 + col] = (u16)bf16r(acc[r]);
  }
  __syncthreads();

  // vectorized global store of xp tile (16 rows x 256 halfs)
#pragma unroll
  for (int rr = 0; rr < 8; ++rr) {
    int idx = rr * 64 + lane;
    int row = idx >> 5, ch = idx & 31;             // 32 chunks of 8 halfs per row
    uint4 v = *(const uint4*)(L + row * 264 + ch * 8);
    *(uint4*)(xp + (node0 + row) * HC + ch * 8) = v;
  }

  // a_src/a_dst: [16 nodes,256] x [256,16] via 8 chained mfma
  f32x4 az = {0.f, 0.f, 0.f, 0.f};
#pragma unroll
  for (int kb = 0; kb < 8; ++kb) {
    bf16x8 a2 = *(const bf16x8*)(L + q * 264 + kb * 32 + g * 8);
    bf16x8 zb = *(const bf16x8*)(Zb + kb * 512 + lane * 8);
    az = __builtin_amdgcn_mfma_f32_16x16x32_bf16(a2, zb, az, 0, 0, 0);
  }
  float* base = (q < 8) ? a_s : a_d;
  int hq = q & 7;
#pragma unroll
  for (int r = 0; r < 4; ++r)
    base[(node0 + 4 * g + r) * HH + hq] = az[r];
}

// ---------- scan phase A: per-1024-block sums ----------
__global__ __launch_bounds__(256) void kscanA(const int* __restrict__ deg,
                                              int* __restrict__ bsum, int n)
{
  __shared__ int ws[4];
  int t = threadIdx.x;
  int i = (int)blockIdx.x * 1024 + t * 4;
  int4 v = make_int4(0, 0, 0, 0);
  if (i + 3 < n) v = *(const int4*)(deg + i);
  else {
    if (i     < n) v.x = deg[i];
    if (i + 1 < n) v.y = deg[i + 1];
    if (i + 2 < n) v.z = deg[i + 2];
    if (i + 3 < n) v.w = deg[i + 3];
  }
  int s = v.x + v.y + v.z + v.w;
#pragma unroll
  for (int mask = 1; mask < 64; mask <<= 1) s += __shfl_xor(s, mask);
  if ((t & 63) == 0) ws[t >> 6] = s;
  __syncthreads();
  if (t == 0) bsum[blockIdx.x] = ws[0] + ws[1] + ws[2] + ws[3];
}

// ---------- scan phase B: exclusive scan of block sums (<=1024 blocks) ----------
__global__ __launch_bounds__(1024) void kscanB(int* __restrict__ bsum, int nb)
{
  __shared__ int wsum[16];
  int t = threadIdx.x, lane = t & 63, wid = t >> 6;
  int v = (t < nb) ? bsum[t] : 0;
  int s = v;
#pragma unroll
  for (int d = 1; d < 64; d <<= 1) { int tt = __shfl_up(s, d); if (lane >= d) s += tt; }
  if (lane == 63) wsum[wid] = s;
  __syncthreads();
  if (wid == 0) {
    int w = (lane < 16) ? wsum[lane] : 0;
#pragma unroll
    for (int d = 1; d < 16; d <<= 1) { int tt = __shfl_up(w, d); if (lane >= d) w += tt; }
    if (lane < 16) wsum[lane] = w;
  }
  __syncthreads();
  int excl = s - v + ((wid > 0) ? wsum[wid - 1] : 0);
  if (t < nb) bsum[t] = excl;
}

// ---------- scan phase C: local rescan + global offset -> offs, cursor ----------
__global__ __launch_bounds__(256) void kscanC(const int* __restrict__ deg,
                                              const int* __restrict__ bsum,
                                              int* __restrict__ offs,
                                              int* __restrict__ cursor, int n)
{
  __shared__ int ws[4];
  int t = threadIdx.x, lane = t & 63, wid = t >> 6;
  int i = (int)blockIdx.x * 1024 + t * 4;
  int4 v = make_int4(0, 0, 0, 0);
  if (i + 3 < n) v = *(const int4*)(deg + i);
  else {
    if (i     < n) v.x = deg[i];
    if (i + 1 < n) v.y = deg[i + 1];
    if (i + 2 < n) v.z = deg[i + 2];
    if (i + 3 < n) v.w = deg[i + 3];
  }
  int tsum = v.x + v.y + v.z + v.w;
  int s = tsum;
#pragma unroll
  for (int d = 1; d < 64; d <<= 1) { int tt = __shfl_up(s, d); if (lane >= d) s += tt; }
  if (lane == 63) ws[wid] = s;
  __syncthreads();
  if (t == 0) {
    int a = ws[0]; ws[0] = 0;
    int b = ws[1]; ws[1] = a; a += b;
    int c = ws[2]; ws[2] = a; a += c;
    ws[3] = a;
  }
  __syncthreads();
  int base = bsum[blockIdx.x] + ws[wid] + (s - tsum);
  if (i     < n) { offs[i]     = base; cursor[i]     = base; } base += v.x;
  if (i + 1 < n) { offs[i + 1] = base; cursor[i + 1] = base; } base += v.y;
  if (i + 2 < n) { offs[i + 2] = base; cursor[i + 2] = base; } base += v.z;
  if (i + 3 < n) { offs[i + 3] = base; cursor[i + 3] = base; }
}

// ---------- CSR scatter ----------
__global__ __launch_bounds__(256) void kscatter(const int* __restrict__ ei, int e,
                                                int* __restrict__ cursor,
                                                int* __restrict__ csr)
{
  int i = (int)blockIdx.x * 1024 + (int)threadIdx.x * 4;
  if (i >= e) return;
  if (i + 3 < e) {
    int4 s4 = *(const int4*)(ei + i);
    int4 d4 = *(const int4*)(ei + e + i);
    csr[atomicAdd(&cursor[d4.x], 1)] = s4.x;
    csr[atomicAdd(&cursor[d4.y], 1)] = s4.y;
    csr[atomicAdd(&cursor[d4.z], 1)] = s4.z;
    csr[atomicAdd(&cursor[d4.w], 1)] = s4.w;
  } else {
    for (int k = 0; k < 4 && i + k < e; ++k) {
      int s = ei[i + k], d = ei[e + i + k];
      csr[atomicAdd(&cursor[d], 1)] = s;
    }
  }
}

// ---------- KAGG: wave-per-node, chunk-of-8 parallel online softmax + agg ----------
__global__ __launch_bounds__(256) void kagg(
    const int* __restrict__ csr, const int* __restrict__ offs,
    const int* __restrict__ deg,
    const float* __restrict__ a_s, const float* __restrict__ a_d,
    const u16* __restrict__ xp, float* __restrict__ og, int n)
{
  int lane = threadIdx.x & 63;
  int node = (int)blockIdx.x * 4 + (threadIdx.x >> 6);
  if (node >= n) return;
  int eg = lane >> 3, ha = lane & 7;
  int hb = eg;                       // head in B layout
  int boff = hb * 32 + (lane & 7) * 4;

  int start = offs[node];
  int dg = deg[node];
  float ad_a  = a_d[(size_t)node * HH + ha];
  float aself = leaky(a_s[(size_t)node * HH + ha] + ad_a);
  float m = aself, dn = 1.f;
  float acc0 = 0.f, acc1 = 0.f, acc2 = 0.f, acc3 = 0.f;

  for (int j0 = 0; j0 < dg; j0 += 8) {
    int rem = dg - j0;
    int cnt = rem < 8 ? rem : 8;
    int idx = j0 + eg;
    int srcl = 0; float al = -3.0e38f;
    if (idx < dg) {
      srcl = csr[start + idx];
      al = leaky(a_s[(size_t)srcl * HH + ha] + ad_a);
    }
    float cm = fmaxf(al, __shfl_xor(al, 8));
    cm = fmaxf(cm, __shfl_xor(cm, 16));
    cm = fmaxf(cm, __shfl_xor(cm, 32));
    float mn = fmaxf(m, cm);
    float scale = __expf(m - mn);
    m = mn;
    float p = (idx < dg) ? __expf(al - m) : 0.f;
    float ps = p + __shfl_xor(p, 8);
    ps += __shfl_xor(ps, 16);
    ps += __shfl_xor(ps, 32);
    dn = dn * scale + ps;
    float sb = __shfl(scale, hb);
    acc0 *= sb; acc1 *= sb; acc2 *= sb; acc3 *= sb;
    if (cnt == 8) {
#pragma unroll
      for (int j = 0; j < 8; ++j) {
        float at = __shfl(p, (j << 3) + hb);
        int s = __shfl(srcl, j << 3);
        uint2 wv = *(const uint2*)(xp + ((size_t)s << 8) + boff);
        acc0 = fmaf(at, bflo(wv.x), acc0);
        acc1 = fmaf(at, bfhi(wv.x), acc1);
        acc2 = fmaf(at, bflo(wv.y), acc2);
        acc3 = fmaf(at, bfhi(wv.y), acc3);
      }
    } else {
      for (int j = 0; j < cnt; ++j) {
        float at = __shfl(p, (j << 3) + hb);
        int s = __shfl(srcl, j << 3);
        uint2 wv = *(const uint2*)(xp + ((size_t)s << 8) + boff);
        acc0 = fmaf(at, bflo(wv.x), acc0);
        acc1 = fmaf(at, bfhi(wv.x), acc1);
        acc2 = fmaf(at, bflo(wv.y), acc2);
        acc3 = fmaf(at, bfhi(wv.y), acc3);
      }
    }
  }
  float sw_a = __expf(aself - m);
  float sw  = __shfl(sw_a, hb);
  float dnb = __shfl(dn, hb);
  {
    uint2 wv = *(const uint2*)(xp + ((size_t)node << 8) + boff);
    acc0 = fmaf(sw, bflo(wv.x), acc0);
    acc1 = fmaf(sw, bfhi(wv.x), acc1);
    acc2 = fmaf(sw, bflo(wv.y), acc2);
    acc3 = fmaf(sw, bfhi(wv.y), acc3);
  }
  float inv = 0.125f / (dnb + 1e-16f);
  acc0 *= inv; acc1 *= inv; acc2 *= inv; acc3 *= inv;
#pragma unroll
  for (int mask = 8; mask < 64; mask <<= 1) {
    acc0 += __shfl_xor(acc0, mask);
    acc1 += __shfl_xor(acc1, mask);
    acc2 += __shfl_xor(acc2, mask);
    acc3 += __shfl_xor(acc3, mask);
  }
  if (lane < 8) {
    *(float4*)(og + (size_t)node * CC + lane * 4) =
      make_float4(acc0, acc1, acc2, acc3);
  }
}

// ---------- K5M: MFMA tail — LN1 + FFN(mfma) + LN2 ----------
__global__ __launch_bounds__(256) void k5m(
    const float* __restrict__ og, const float* __restrict__ x,
    const float* __restrict__ bg,
    const u16* __restrict__ V1b, const u16* __restrict__ V2b,
    const float* __restrict__ b1, const float* __restrict__ b2,
    const float* __restrict__ g1, const float* __restrict__ be1,
    const float* __restrict__ g2, const float* __restrict__ be2,
    float* __restrict__ out, int n)
{
  __shared__ u16   lh[4][16 * 40];                 // h bf16 [16][32] pad 40
  __shared__ u16   lf[4][16 * 136];                // f bf16 [16][128] pad 136
  __shared__ float lo[4][16 * 36];                 // fp32 [16][32] pad 36
  int wid = threadIdx.x >> 6, lane = threadIdx.x & 63;
  int q = lane & 15, g = lane >> 4;
  long node0 = (long)((int)blockIdx.x * 4 + wid) * 16;
  if (node0 + 16 > n) node0 = n - 16;
  u16* LH = lh[wid]; u16* LF = lf[wid]; float* LO = lo[wid];

  // stage og + x + bg cooperatively (coalesced)
  {
    int row = lane >> 2, off = (lane & 3) * 8;
    const float* o8 = og + (node0 + row) * CC + off;
    const float* x8 = x  + (node0 + row) * CC + off;
    float4 a0 = *(const float4*)o8, a1 = *(const float4*)(o8 + 4);
    float4 c0 = *(const float4*)x8, c1 = *(const float4*)(x8 + 4);
    float4 bg0 = *(const float4*)(bg + off), bg1 = *(const float4*)(bg + off + 4);
    float4 s0 = make_float4(a0.x + c0.x + bg0.x, a0.y + c0.y + bg0.y,
                            a0.z + c0.z + bg0.z, a0.w + c0.w + bg0.w);
    float4 s1 = make_float4(a1.x + c1.x + bg1.x, a1.y + c1.y + bg1.y,
                            a1.z + c1.z + bg1.z, a1.w + c1.w + bg1.w);
    *(float4*)(LO + row * 36 + off)     = s0;
    *(float4*)(LO + row * 36 + off + 4) = s1;
  }
  __syncthreads();

  float hv[32];
  if (lane < 16) {                                 // owner lane q: LN1 for node0+q
#pragma unroll
    for (int i = 0; i < 8; ++i) {
      float4 t = *(const float4*)(LO + q * 36 + i * 4);
      hv[4*i] = t.x; hv[4*i+1] = t.y; hv[4*i+2] = t.z; hv[4*i+3] = t.w;
    }
    float mu = 0.f;
#pragma unroll
    for (int c = 0; c < 32; ++c) mu += hv[c];
    mu *= (1.f / 32.f);
    float var = 0.f;
#pragma unroll
    for (int c = 0; c < 32; ++c) { float t = hv[c] - mu; var = fmaf(t, t, var); }
    float rs = rsqrtf(var * (1.f / 32.f) + LNEPS);
#pragma unroll
    for (int c = 0; c < 32; ++c) hv[c] = (hv[c] - mu) * rs * g1[c] + be1[c];
    uint* dst = (uint*)(LH + q * 40);
#pragma unroll
    for (int i = 0; i < 16; ++i)
      dst[i] = bf16r(hv[2*i]) | (bf16r(hv[2*i+1]) << 16);
  }
  __syncthreads();

  bf16x8 ah = *(const bf16x8*)(LH + q * 40 + g * 8);
  // ff1 + bias + relu -> LF
#pragma unroll
  for (int nb = 0; nb < 8; ++nb) {
    bf16x8 v1 = *(const bf16x8*)(V1b + nb * 512 + lane * 8);
    f32x4 acc = {0.f, 0.f, 0.f, 0.f};
    acc = __builtin_amdgcn_mfma_f32_16x16x32_bf16(ah, v1, acc, 0, 0, 0);
    int col = 16 * nb + q;
    float bias = b1[col];
#pragma unroll
    for (int r = 0; r < 4; ++r) {
      float f = fmaxf(acc[r] + bias, 0.f);
      LF[(4 * g + r) * 136 + col] = (u16)bf16r(f);
    }
  }
  __syncthreads();

  // ff2: [16,128] x [128,32]
  f32x4 a20 = {0.f, 0.f, 0.f, 0.f}, a21 = {0.f, 0.f, 0.f, 0.f};
#pragma unroll
  for (int kb = 0; kb < 4; ++kb) {
    bf16x8 af2 = *(const bf16x8*)(LF + q * 136 + kb * 32 + g * 8);
    bf16x8 v20 = *(const bf16x8*)(V2b + (kb * 2 + 0) * 512 + lane * 8);
    bf16x8 v21 = *(const bf16x8*)(V2b + (kb * 2 + 1) * 512 + lane * 8);
    a20 = __builtin_amdgcn_mfma_f32_16x16x32_bf16(af2, v20, a20, 0, 0, 0);
    a21 = __builtin_amdgcn_mfma_f32_16x16x32_bf16(af2, v21, a21, 0, 0, 0);
  }
  __syncthreads();                                 // LO reads (phase 1) long done
#pragma unroll
  for (int r = 0; r < 4; ++r) {
    LO[(4 * g + r) * 36 + q]      = a20[r];
    LO[(4 * g + r) * 36 + 16 + q] = a21[r];
  }
  __syncthreads();

  if (lane < 16) {                                 // owner: +b2 +h residual, LN2, store
    float ov[32];
#pragma unroll
    for (int i = 0; i < 8; ++i) {
      float4 t = *(const float4*)(LO + q * 36 + i * 4);
      ov[4*i] = t.x; ov[4*i+1] = t.y; ov[4*i+2] = t.z; ov[4*i+3] = t.w;
    }
#pragma unroll
    for (int c = 0; c < 32; ++c) ov[c] += b2[c] + hv[c];
    float mu2 = 0.f;
#pragma unroll
    for (int c = 0; c < 32; ++c) mu2 += ov[c];
    mu2 *= (1.f / 32.f);
    float var2 = 0.f;
#pragma unroll
    for (int c = 0; c < 32; ++c) { float t = ov[c] - mu2; var2 = fmaf(t, t, var2); }
    float rs2 = rsqrtf(var2 * (1.f / 32.f) + LNEPS);
    float* op = out + (node0 + q) * CC;
#pragma unroll
    for (int i = 0; i < 8; ++i) {
      float4 o;
      o.x = (ov[4*i]   - mu2) * rs2 * g2[4*i]   + be2[4*i];
      o.y = (ov[4*i+1] - mu2) * rs2 * g2[4*i+1] + be2[4*i+1];
      o.z = (ov[4*i+2] - mu2) * rs2 * g2[4*i+2] + be2[4*i+2];
      o.w = (ov[4*i+3] - mu2) * rs2 * g2[4*i+3] + be2[4*i+3];
      *(float4*)(op + i * 4) = o;
    }
  }
}

// ---------- launch ----------
extern "C" void kernel_launch(void* const* d_in, const int* in_sizes, int n_in,
                              void* d_out, int out_size, void* d_ws, size_t ws_size,
                              hipStream_t stream)
{
  const float* x    = (const float*)d_in[0];
  const int*   ei   = (const int*)d_in[1];
  const float* W    = (const float*)d_in[2];
  const float* atts = (const float*)d_in[3];
  const float* attd = (const float*)d_in[4];
  const float* bg   = (const float*)d_in[5];
  const float* w1   = (const float*)d_in[6];
  const float* b1   = (const float*)d_in[7];
  const float* w2   = (const float*)d_in[8];
  const float* b2   = (const float*)d_in[9];
  const float* g1   = (const float*)d_in[10];
  const float* be1  = (const float*)d_in[11];
  const float* g2   = (const float*)d_in[12];
  const float* be2  = (const float*)d_in[13];

  int n = in_sizes[0] / CC;
  int e = in_sizes[1] / 2;

  uint8_t* ws = (uint8_t*)d_ws;
  size_t o = 0;
  u16*  xp  = (u16*)(ws + o);  o += (size_t)n * HC * 2; o = (o + 255) & ~(size_t)255;
  float* a_s = (float*)(ws + o); o += (size_t)n * HH * 4;
  float* a_d = (float*)(ws + o); o += (size_t)n * HH * 4;
  float* og  = (float*)(ws + o); o += (size_t)n * CC * 4;
  int* deg    = (int*)(ws + o); o += (size_t)n * 4;
  int* offs   = (int*)(ws + o); o += (size_t)n * 4;
  int* cursor = (int*)(ws + o); o += (size_t)n * 4;
  int* csr    = (int*)(ws + o); o += (size_t)e * 4;
  int* bsum   = (int*)(ws + o); o += 4096;
  u16* Wb  = (u16*)(ws + o); o += 16 * 512 * 2;
  u16* Zb  = (u16*)(ws + o); o += 8 * 512 * 2;
  u16* V1b = (u16*)(ws + o); o += 8 * 512 * 2;
  u16* V2b = (u16*)(ws + o); o += 8 * 512 * 2;

  hipMemsetAsync(deg, 0, (size_t)n * 4, stream);

  int nwaves = (n + 15) / 16;
  int nbc   = (nwaves + 3) / 4;      // mfma compute blocks (4 waves each)
  int nb_e4 = (e + 1023) / 1024;
  int nb_s  = (n + 1023) / 1024;

  klayout <<<1, 256, 0, stream>>>(W, atts, attd, w1, w2, Wb, Zb, V1b, V2b);
  k1m     <<<nbc + nb_e4, 256, 0, stream>>>(x, Wb, Zb, ei, xp, a_s, a_d, deg, n, e, nbc);
  kscanA  <<<nb_s, 256, 0, stream>>>(deg, bsum, n);
  kscanB  <<<1, 1024, 0, stream>>>(bsum, nb_s);
  kscanC  <<<nb_s, 256, 0, stream>>>(deg, bsum, offs, cursor, n);
  kscatter<<<nb_e4, 256, 0, stream>>>(ei, e, cursor, csr);
  kagg    <<<(n + 3) / 4, 256, 0, stream>>>(csr, offs, deg, a_s, a_d, xp, og, n);
  k5m     <<<nbc, 256, 0, stream>>>(og, x, bg, V1b, V2b, b1, b2, g1, be1, g2, be2,
                                    (float*)d_out, n);
}

// Round 5
// 363.411 us; speedup vs baseline: 11.9006x; 1.0857x over previous
//
#include <hip/hip_runtime.h>
#include <stdint.h>

#define HH 8
#define CC 32
#define HC 256   // H*C
#define FF 128
#define NEG 0.2f
#define LNEPS 1e-5f

typedef __attribute__((ext_vector_type(8))) short bf16x8;
typedef __attribute__((ext_vector_type(4))) float f32x4;
typedef unsigned short u16;

// ---------- helpers ----------
__device__ inline unsigned bf16r(float f) {           // round-to-nearest-even bf16
  unsigned u = __float_as_uint(f);
  return (u + 0x7fffu + ((u >> 16) & 1u)) >> 16;
}
__device__ inline float bflo(unsigned w) { return __uint_as_float(w << 16); }
__device__ inline float bfhi(unsigned w) { return __uint_as_float(w & 0xffff0000u); }
__device__ inline float leaky(float v) { return v >= 0.f ? v : NEG * v; }
// byte extract -> float (v_cvt_f32_ubyte0..3)
__device__ inline float ub0(unsigned w) { return (float)(w & 0xffu); }
__device__ inline float ub1(unsigned w) { return (float)((w >> 8) & 0xffu); }
__device__ inline float ub2(unsigned w) { return (float)((w >> 16) & 0xffu); }
__device__ inline float ub3(unsigned w) { return (float)(w >> 24); }

// ---------- KLAYOUT: repack weights into MFMA B-fragment layout (bf16) ----------
// B-frag (16x16x32): lane l supplies B[8*(l>>4)+j][l&15], j=0..7 contiguous.
__global__ __launch_bounds__(256) void klayout(
    const float* __restrict__ W, const float* __restrict__ atts,
    const float* __restrict__ attd, const float* __restrict__ w1,
    const float* __restrict__ w2,
    u16* __restrict__ Wb, u16* __restrict__ Zb,
    u16* __restrict__ V1b, u16* __restrict__ V2b)
{
  int t = threadIdx.x;
  for (int i = t; i < 16 * 512; i += 256) {        // Wb: W_gat [32,256]
    int j = i & 7, l = (i >> 3) & 63, nb = i >> 9;
    int k = 8 * (l >> 4) + j, c = 16 * nb + (l & 15);
    Wb[i] = (u16)bf16r(W[k * HC + c]);
  }
  for (int i = t; i < 8 * 512; i += 256) {         // Zb: [256,16] = [atts|attd] blockdiag
    int j = i & 7, l = (i >> 3) & 63, kb = i >> 9;
    int k = 32 * kb + 8 * (l >> 4) + j;            // channel 0..255
    int tc = l & 15;
    float v = 0.f;
    if (tc < 8)  { if ((k >> 5) == tc)     v = atts[tc * 32 + (k & 31)]; }
    else         { if ((k >> 5) == tc - 8) v = attd[(tc - 8) * 32 + (k & 31)]; }
    Zb[i] = (u16)bf16r(v);
  }
  for (int i = t; i < 8 * 512; i += 256) {         // V1b: w1 [32,128]
    int j = i & 7, l = (i >> 3) & 63, nb = i >> 9;
    int k = 8 * (l >> 4) + j, c = 16 * nb + (l & 15);
    V1b[i] = (u16)bf16r(w1[k * FF + c]);
  }
  for (int i = t; i < 8 * 512; i += 256) {         // V2b: w2 [128,32]
    int j = i & 7, l = (i >> 3) & 63, kn = i >> 9;
    int kb = kn >> 1, nb2 = kn & 1;
    int k = 32 * kb + 8 * (l >> 4) + j, c = 16 * nb2 + (l & 15);
    V2b[i] = (u16)bf16r(w2[k * CC + c]);
  }
}

// ---------- K1M: MFMA xp=x@W -> int8 rows + per-(node,head) scale + a dots + hist ----------
__global__ __launch_bounds__(256) void k1m(
    const float* __restrict__ x, const u16* __restrict__ Wb,
    const u16* __restrict__ Zb, const int* __restrict__ ei,
    signed char* __restrict__ xq, float* __restrict__ asc,
    float* __restrict__ a_d, int* __restrict__ deg, int n, int e, int nbc)
{
  if ((int)blockIdx.x >= nbc) {                    // histogram role
    int i = ((int)blockIdx.x - nbc) * 1024 + (int)threadIdx.x * 4;
    if (i >= e) return;
    const int* dst = ei + e;
    if (i + 3 < e) {
      int4 d4 = *(const int4*)(dst + i);
      atomicAdd(&deg[d4.x], 1); atomicAdd(&deg[d4.y], 1);
      atomicAdd(&deg[d4.z], 1); atomicAdd(&deg[d4.w], 1);
    } else {
      for (int k = 0; k < 4 && i + k < e; ++k) atomicAdd(&deg[dst[i + k]], 1);
    }
    return;
  }
  __shared__ u16 lt[4][16 * 264];                  // per-wave [16 rows][264 halfs]
  __shared__ float lsc[4][16][8];                  // per-wave rinv = 127/rowmax
  int wid = threadIdx.x >> 6, lane = threadIdx.x & 63;
  int q = lane & 15, g = lane >> 4;
  long node0 = (long)((int)blockIdx.x * 4 + wid) * 16;
  if (node0 + 16 > n) node0 = n - 16;              // overlap tail: duplicate identical writes
  u16* L = lt[wid];

  // A-frag: x[node0+q][8g..8g+7] -> bf16
  const float* xr = x + (node0 + q) * CC + 8 * g;
  float4 xa = *(const float4*)xr, xb = *(const float4*)(xr + 4);
  bf16x8 af;
  af[0] = (short)bf16r(xa.x); af[1] = (short)bf16r(xa.y);
  af[2] = (short)bf16r(xa.z); af[3] = (short)bf16r(xa.w);
  af[4] = (short)bf16r(xb.x); af[5] = (short)bf16r(xb.y);
  af[6] = (short)bf16r(xb.z); af[7] = (short)bf16r(xb.w);

#pragma unroll
  for (int nb = 0; nb < 16; ++nb) {
    bf16x8 bf = *(const bf16x8*)(Wb + nb * 512 + lane * 8);
    f32x4 acc = {0.f, 0.f, 0.f, 0.f};
    acc = __builtin_amdgcn_mfma_f32_16x16x32_bf16(af, bf, acc, 0, 0, 0);
    int col = 16 * nb + q;
#pragma unroll
    for (int r = 0; r < 4; ++r)
      L[(4 * g + r) * 264 + col] = (u16)bf16r(acc[r]);
  }
  __syncthreads();

  // a_src/a_dst: [16 nodes,256] x [256,16] via 8 chained mfma
  f32x4 az = {0.f, 0.f, 0.f, 0.f};
#pragma unroll
  for (int kb = 0; kb < 8; ++kb) {
    bf16x8 a2 = *(const bf16x8*)(L + q * 264 + kb * 32 + g * 8);
    bf16x8 zb = *(const bf16x8*)(Zb + kb * 512 + lane * 8);
    az = __builtin_amdgcn_mfma_f32_16x16x32_bf16(a2, zb, az, 0, 0, 0);
  }
  int hq = q & 7;
  if (q < 8) {                                     // a_src -> asc[.x]
#pragma unroll
    for (int r = 0; r < 4; ++r)
      asc[((node0 + 4 * g + r) * HH + hq) * 2] = az[r];
  } else {                                         // a_dst
#pragma unroll
    for (int r = 0; r < 4; ++r)
      a_d[(node0 + 4 * g + r) * HH + hq] = az[r];
  }

  // per-(row,head) absmax -> scale (asc[.y]) + rinv (LDS)
#pragma unroll
  for (int t2 = 0; t2 < 2; ++t2) {
    int task = t2 * 64 + lane;                     // 128 tasks
    int r = task >> 3, h = task & 7;
    const unsigned* p = (const unsigned*)(L + r * 264 + h * 32);
    float mx = 0.f;
#pragma unroll
    for (int i = 0; i < 16; ++i) {
      unsigned w = p[i];
      mx = fmaxf(mx, fmaxf(fabsf(bflo(w)), fabsf(bfhi(w))));
    }
    float scale = mx * (1.f / 127.f);
    float rinv = (mx > 0.f) ? 127.f / mx : 0.f;
    asc[((node0 + r) * HH + h) * 2 + 1] = scale;
    lsc[wid][r][h] = rinv;
  }
  __syncthreads();

  // int8 encode + store: 16 rows x 64 dwords, 16 dwords per lane
#pragma unroll
  for (int i = 0; i < 16; ++i) {
    int d = i * 64 + lane;
    int r = d >> 6, c = d & 63;                    // c: dword within row
    int h = c >> 3;
    float rv = lsc[wid][r][h];
    const unsigned* p = (const unsigned*)(L + r * 264) + (c << 1);
    unsigned w0 = p[0], w1 = p[1];
    int q0 = __float2int_rn(bflo(w0) * rv);
    int q1 = __float2int_rn(bfhi(w0) * rv);
    int q2 = __float2int_rn(bflo(w1) * rv);
    int q3 = __float2int_rn(bfhi(w1) * rv);
    q0 = min(max(q0, -127), 127) + 128;
    q1 = min(max(q1, -127), 127) + 128;
    q2 = min(max(q2, -127), 127) + 128;
    q3 = min(max(q3, -127), 127) + 128;
    unsigned pk = (unsigned)q0 | ((unsigned)q1 << 8) |
                  ((unsigned)q2 << 16) | ((unsigned)q3 << 24);
    *(unsigned*)(xq + (node0 + r) * HC + c * 4) = pk;
  }
}

// ---------- scan phase A ----------
__global__ __launch_bounds__(256) void kscanA(const int* __restrict__ deg,
                                              int* __restrict__ bsum, int n)
{
  __shared__ int ws[4];
  int t = threadIdx.x;
  int i = (int)blockIdx.x * 1024 + t * 4;
  int4 v = make_int4(0, 0, 0, 0);
  if (i + 3 < n) v = *(const int4*)(deg + i);
  else {
    if (i     < n) v.x = deg[i];
    if (i + 1 < n) v.y = deg[i + 1];
    if (i + 2 < n) v.z = deg[i + 2];
    if (i + 3 < n) v.w = deg[i + 3];
  }
  int s = v.x + v.y + v.z + v.w;
#pragma unroll
  for (int mask = 1; mask < 64; mask <<= 1) s += __shfl_xor(s, mask);
  if ((t & 63) == 0) ws[t >> 6] = s;
  __syncthreads();
  if (t == 0) bsum[blockIdx.x] = ws[0] + ws[1] + ws[2] + ws[3];
}

// ---------- scan phase B ----------
__global__ __launch_bounds__(1024) void kscanB(int* __restrict__ bsum, int nb)
{
  __shared__ int wsum[16];
  int t = threadIdx.x, lane = t & 63, wid = t >> 6;
  int v = (t < nb) ? bsum[t] : 0;
  int s = v;
#pragma unroll
  for (int d = 1; d < 64; d <<= 1) { int tt = __shfl_up(s, d); if (lane >= d) s += tt; }
  if (lane == 63) wsum[wid] = s;
  __syncthreads();
  if (wid == 0) {
    int w = (lane < 16) ? wsum[lane] : 0;
#pragma unroll
    for (int d = 1; d < 16; d <<= 1) { int tt = __shfl_up(w, d); if (lane >= d) w += tt; }
    if (lane < 16) wsum[lane] = w;
  }
  __syncthreads();
  int excl = s - v + ((wid > 0) ? wsum[wid - 1] : 0);
  if (t < nb) bsum[t] = excl;
}

// ---------- scan phase C ----------
__global__ __launch_bounds__(256) void kscanC(const int* __restrict__ deg,
                                              const int* __restrict__ bsum,
                                              int* __restrict__ offs,
                                              int* __restrict__ cursor, int n)
{
  __shared__ int ws[4];
  int t = threadIdx.x, lane = t & 63, wid = t >> 6;
  int i = (int)blockIdx.x * 1024 + t * 4;
  int4 v = make_int4(0, 0, 0, 0);
  if (i + 3 < n) v = *(const int4*)(deg + i);
  else {
    if (i     < n) v.x = deg[i];
    if (i + 1 < n) v.y = deg[i + 1];
    if (i + 2 < n) v.z = deg[i + 2];
    if (i + 3 < n) v.w = deg[i + 3];
  }
  int tsum = v.x + v.y + v.z + v.w;
  int s = tsum;
#pragma unroll
  for (int d = 1; d < 64; d <<= 1) { int tt = __shfl_up(s, d); if (lane >= d) s += tt; }
  if (lane == 63) ws[wid] = s;
  __syncthreads();
  if (t == 0) {
    int a = ws[0]; ws[0] = 0;
    int b = ws[1]; ws[1] = a; a += b;
    int c = ws[2]; ws[2] = a; a += c;
    ws[3] = a;
  }
  __syncthreads();
  int base = bsum[blockIdx.x] + ws[wid] + (s - tsum);
  if (i     < n) { offs[i]     = base; cursor[i]     = base; } base += v.x;
  if (i + 1 < n) { offs[i + 1] = base; cursor[i + 1] = base; } base += v.y;
  if (i + 2 < n) { offs[i + 2] = base; cursor[i + 2] = base; } base += v.z;
  if (i + 3 < n) { offs[i + 3] = base; cursor[i + 3] = base; }
}

// ---------- CSR scatter ----------
__global__ __launch_bounds__(256) void kscatter(const int* __restrict__ ei, int e,
                                                int* __restrict__ cursor,
                                                int* __restrict__ csr)
{
  int i = (int)blockIdx.x * 1024 + (int)threadIdx.x * 4;
  if (i >= e) return;
  if (i + 3 < e) {
    int4 s4 = *(const int4*)(ei + i);
    int4 d4 = *(const int4*)(ei + e + i);
    csr[atomicAdd(&cursor[d4.x], 1)] = s4.x;
    csr[atomicAdd(&cursor[d4.y], 1)] = s4.y;
    csr[atomicAdd(&cursor[d4.z], 1)] = s4.z;
    csr[atomicAdd(&cursor[d4.w], 1)] = s4.w;
  } else {
    for (int k = 0; k < 4 && i + k < e; ++k) {
      int s = ei[i + k], d = ei[e + i + k];
      csr[atomicAdd(&cursor[d], 1)] = s;
    }
  }
}

// ---------- KAGG: wave-per-node, chunk-of-8 online softmax + int8 value gather ----------
// phase-A layout: eg=lane>>3 (edge in chunk), ha=lane&7 (head)
// phase-B layout: hb=lane>>3 (head), (lane&7)*4 channels
__global__ __launch_bounds__(256) void kagg(
    const int* __restrict__ csr, const int* __restrict__ offs,
    const int* __restrict__ deg,
    const float2* __restrict__ asc, const float* __restrict__ a_d,
    const signed char* __restrict__ xq, float* __restrict__ og, int n)
{
  int lane = threadIdx.x & 63;
  int node = (int)blockIdx.x * 4 + (threadIdx.x >> 6);
  if (node >= n) return;
  int eg = lane >> 3, ha = lane & 7;
  int hb = eg;                         // head in B layout
  int boff = hb * 32 + (lane & 7) * 4; // byte offset in 256B row

  int start = offs[node];
  int dg = deg[node];
  float ad_a  = a_d[(size_t)node * HH + ha];
  float aself = leaky(asc[(size_t)node * HH + ha].x + ad_a);
  float m = aself, dn = 1.f;
  float acc0 = 0.f, acc1 = 0.f, acc2 = 0.f, acc3 = 0.f, osum = 0.f;

  for (int j0 = 0; j0 < dg; j0 += 8) {
    int rem = dg - j0;
    int cnt = rem < 8 ? rem : 8;
    int idx = j0 + eg;
    int srcl = 0; float al = -3.0e38f; float sc = 0.f;
    if (idx < dg) {
      srcl = csr[start + idx];
      float2 v = asc[(size_t)srcl * HH + ha];
      al = leaky(v.x + ad_a);
      sc = v.y;
    }
    float cm = fmaxf(al, __shfl_xor(al, 8));
    cm = fmaxf(cm, __shfl_xor(cm, 16));
    cm = fmaxf(cm, __shfl_xor(cm, 32));
    float mn = fmaxf(m, cm);
    float scale = __expf(m - mn);
    m = mn;
    float p = (idx < dg) ? __expf(al - m) : 0.f;
    float ps = p + __shfl_xor(p, 8);
    ps += __shfl_xor(ps, 16);
    ps += __shfl_xor(ps, 32);
    dn = dn * scale + ps;
    float sb = __shfl(scale, hb);
    acc0 *= sb; acc1 *= sb; acc2 *= sb; acc3 *= sb; osum *= sb;
    if (cnt == 8) {
#pragma unroll
      for (int j = 0; j < 8; ++j) {
        float at = __shfl(p, (j << 3) + hb);
        float sj = __shfl(sc, (j << 3) + hb);
        int s = __shfl(srcl, j << 3);
        float wt = at * sj;
        unsigned w = *(const unsigned*)(xq + ((size_t)s << 8) + boff);
        osum += wt;
        acc0 = fmaf(ub0(w), wt, acc0);
        acc1 = fmaf(ub1(w), wt, acc1);
        acc2 = fmaf(ub2(w), wt, acc2);
        acc3 = fmaf(ub3(w), wt, acc3);
      }
    } else {
      for (int j = 0; j < cnt; ++j) {
        float at = __shfl(p, (j << 3) + hb);
        float sj = __shfl(sc, (j << 3) + hb);
        int s = __shfl(srcl, j << 3);
        float wt = at * sj;
        unsigned w = *(const unsigned*)(xq + ((size_t)s << 8) + boff);
        osum += wt;
        acc0 = fmaf(ub0(w), wt, acc0);
        acc1 = fmaf(ub1(w), wt, acc1);
        acc2 = fmaf(ub2(w), wt, acc2);
        acc3 = fmaf(ub3(w), wt, acc3);
      }
    }
  }
  // self loop
  float sw  = __shfl(__expf(aself - m), hb);
  float dnb = __shfl(dn, hb);
  {
    float ssc = asc[(size_t)node * HH + hb].y;
    float wt = sw * ssc;
    unsigned w = *(const unsigned*)(xq + ((size_t)node << 8) + boff);
    osum += wt;
    acc0 = fmaf(ub0(w), wt, acc0);
    acc1 = fmaf(ub1(w), wt, acc1);
    acc2 = fmaf(ub2(w), wt, acc2);
    acc3 = fmaf(ub3(w), wt, acc3);
  }
  float corr = -128.f * osum;
  float inv = 0.125f / (dnb + 1e-16f);
  acc0 = (acc0 + corr) * inv;
  acc1 = (acc1 + corr) * inv;
  acc2 = (acc2 + corr) * inv;
  acc3 = (acc3 + corr) * inv;
#pragma unroll
  for (int mask = 8; mask < 64; mask <<= 1) {
    acc0 += __shfl_xor(acc0, mask);
    acc1 += __shfl_xor(acc1, mask);
    acc2 += __shfl_xor(acc2, mask);
    acc3 += __shfl_xor(acc3, mask);
  }
  if (lane < 8) {
    *(float4*)(og + (size_t)node * CC + lane * 4) =
      make_float4(acc0, acc1, acc2, acc3);
  }
}

// ---------- K5M: MFMA tail — LN1 + FFN(mfma) + LN2 ----------
__global__ __launch_bounds__(256) void k5m(
    const float* __restrict__ og, const float* __restrict__ x,
    const float* __restrict__ bg,
    const u16* __restrict__ V1b, const u16* __restrict__ V2b,
    const float* __restrict__ b1, const float* __restrict__ b2,
    const float* __restrict__ g1, const float* __restrict__ be1,
    const float* __restrict__ g2, const float* __restrict__ be2,
    float* __restrict__ out, int n)
{
  __shared__ u16   lh[4][16 * 40];                 // h bf16 [16][32] pad 40
  __shared__ u16   lf[4][16 * 136];                // f bf16 [16][128] pad 136
  __shared__ float lo[4][16 * 36];                 // fp32 [16][32] pad 36
  int wid = threadIdx.x >> 6, lane = threadIdx.x & 63;
  int q = lane & 15, g = lane >> 4;
  long node0 = (long)((int)blockIdx.x * 4 + wid) * 16;
  if (node0 + 16 > n) node0 = n - 16;
  u16* LH = lh[wid]; u16* LF = lf[wid]; float* LO = lo[wid];

  {
    int row = lane >> 2, off = (lane & 3) * 8;
    const float* o8 = og + (node0 + row) * CC + off;
    const float* x8 = x  + (node0 + row) * CC + off;
    float4 a0 = *(const float4*)o8, a1 = *(const float4*)(o8 + 4);
    float4 c0 = *(const float4*)x8, c1 = *(const float4*)(x8 + 4);
    float4 bg0 = *(const float4*)(bg + off), bg1 = *(const float4*)(bg + off + 4);
    float4 s0 = make_float4(a0.x + c0.x + bg0.x, a0.y + c0.y + bg0.y,
                            a0.z + c0.z + bg0.z, a0.w + c0.w + bg0.w);
    float4 s1 = make_float4(a1.x + c1.x + bg1.x, a1.y + c1.y + bg1.y,
                            a1.z + c1.z + bg1.z, a1.w + c1.w + bg1.w);
    *(float4*)(LO + row * 36 + off)     = s0;
    *(float4*)(LO + row * 36 + off + 4) = s1;
  }
  __syncthreads();

  float hv[32];
  if (lane < 16) {
#pragma unroll
    for (int i = 0; i < 8; ++i) {
      float4 t = *(const float4*)(LO + q * 36 + i * 4);
      hv[4*i] = t.x; hv[4*i+1] = t.y; hv[4*i+2] = t.z; hv[4*i+3] = t.w;
    }
    float mu = 0.f;
#pragma unroll
    for (int c = 0; c < 32; ++c) mu += hv[c];
    mu *= (1.f / 32.f);
    float var = 0.f;
#pragma unroll
    for (int c = 0; c < 32; ++c) { float t = hv[c] - mu; var = fmaf(t, t, var); }
    float rs = rsqrtf(var * (1.f / 32.f) + LNEPS);
#pragma unroll
    for (int c = 0; c < 32; ++c) hv[c] = (hv[c] - mu) * rs * g1[c] + be1[c];
    uint* dst = (uint*)(LH + q * 40);
#pragma unroll
    for (int i = 0; i < 16; ++i)
      dst[i] = bf16r(hv[2*i]) | (bf16r(hv[2*i+1]) << 16);
  }
  __syncthreads();

  bf16x8 ah = *(const bf16x8*)(LH + q * 40 + g * 8);
#pragma unroll
  for (int nb = 0; nb < 8; ++nb) {
    bf16x8 v1 = *(const bf16x8*)(V1b + nb * 512 + lane * 8);
    f32x4 acc = {0.f, 0.f, 0.f, 0.f};
    acc = __builtin_amdgcn_mfma_f32_16x16x32_bf16(ah, v1, acc, 0, 0, 0);
    int col = 16 * nb + q;
    float bias = b1[col];
#pragma unroll
    for (int r = 0; r < 4; ++r) {
      float f = fmaxf(acc[r] + bias, 0.f);
      LF[(4 * g + r) * 136 + col] = (u16)bf16r(f);
    }
  }
  __syncthreads();

  f32x4 a20 = {0.f, 0.f, 0.f, 0.f}, a21 = {0.f, 0.f, 0.f, 0.f};
#pragma unroll
  for (int kb = 0; kb < 4; ++kb) {
    bf16x8 af2 = *(const bf16x8*)(LF + q * 136 + kb * 32 + g * 8);
    bf16x8 v20 = *(const bf16x8*)(V2b + (kb * 2 + 0) * 512 + lane * 8);
    bf16x8 v21 = *(const bf16x8*)(V2b + (kb * 2 + 1) * 512 + lane * 8);
    a20 = __builtin_amdgcn_mfma_f32_16x16x32_bf16(af2, v20, a20, 0, 0, 0);
    a21 = __builtin_amdgcn_mfma_f32_16x16x32_bf16(af2, v21, a21, 0, 0, 0);
  }
  __syncthreads();
#pragma unroll
  for (int r = 0; r < 4; ++r) {
    LO[(4 * g + r) * 36 + q]      = a20[r];
    LO[(4 * g + r) * 36 + 16 + q] = a21[r];
  }
  __syncthreads();

  if (lane < 16) {
    float ov[32];
#pragma unroll
    for (int i = 0; i < 8; ++i) {
      float4 t = *(const float4*)(LO + q * 36 + i * 4);
      ov[4*i] = t.x; ov[4*i+1] = t.y; ov[4*i+2] = t.z; ov[4*i+3] = t.w;
    }
#pragma unroll
    for (int c = 0; c < 32; ++c) ov[c] += b2[c] + hv[c];
    float mu2 = 0.f;
#pragma unroll
    for (int c = 0; c < 32; ++c) mu2 += ov[c];
    mu2 *= (1.f / 32.f);
    float var2 = 0.f;
#pragma unroll
    for (int c = 0; c < 32; ++c) { float t = ov[c] - mu2; var2 = fmaf(t, t, var2); }
    float rs2 = rsqrtf(var2 * (1.f / 32.f) + LNEPS);
    float* op = out + (node0 + q) * CC;
#pragma unroll
    for (int i = 0; i < 8; ++i) {
      float4 o;
      o.x = (ov[4*i]   - mu2) * rs2 * g2[4*i]   + be2[4*i];
      o.y = (ov[4*i+1] - mu2) * rs2 * g2[4*i+1] + be2[4*i+1];
      o.z = (ov[4*i+2] - mu2) * rs2 * g2[4*i+2] + be2[4*i+2];
      o.w = (ov[4*i+3] - mu2) * rs2 * g2[4*i+3] + be2[4*i+3];
      *(float4*)(op + i * 4) = o;
    }
  }
}

// ---------- launch ----------
extern "C" void kernel_launch(void* const* d_in, const int* in_sizes, int n_in,
                              void* d_out, int out_size, void* d_ws, size_t ws_size,
                              hipStream_t stream)
{
  const float* x    = (const float*)d_in[0];
  const int*   ei   = (const int*)d_in[1];
  const float* W    = (const float*)d_in[2];
  const float* atts = (const float*)d_in[3];
  const float* attd = (const float*)d_in[4];
  const float* bg   = (const float*)d_in[5];
  const float* w1   = (const float*)d_in[6];
  const float* b1   = (const float*)d_in[7];
  const float* w2   = (const float*)d_in[8];
  const float* b2   = (const float*)d_in[9];
  const float* g1   = (const float*)d_in[10];
  const float* be1  = (const float*)d_in[11];
  const float* g2   = (const float*)d_in[12];
  const float* be2  = (const float*)d_in[13];

  int n = in_sizes[0] / CC;
  int e = in_sizes[1] / 2;

  uint8_t* ws = (uint8_t*)d_ws;
  size_t o = 0;
  signed char* xq = (signed char*)(ws + o); o += (size_t)n * HC; o = (o + 255) & ~(size_t)255;
  float* asc = (float*)(ws + o); o += (size_t)n * HH * 8;   // float2 per (node,head)
  float* a_d = (float*)(ws + o); o += (size_t)n * HH * 4;
  float* og  = (float*)(ws + o); o += (size_t)n * CC * 4;
  int* deg    = (int*)(ws + o); o += (size_t)n * 4;
  int* offs   = (int*)(ws + o); o += (size_t)n * 4;
  int* cursor = (int*)(ws + o); o += (size_t)n * 4;
  int* csr    = (int*)(ws + o); o += (size_t)e * 4;
  int* bsum   = (int*)(ws + o); o += 4096;
  u16* Wb  = (u16*)(ws + o); o += 16 * 512 * 2;
  u16* Zb  = (u16*)(ws + o); o += 8 * 512 * 2;
  u16* V1b = (u16*)(ws + o); o += 8 * 512 * 2;
  u16* V2b = (u16*)(ws + o); o += 8 * 512 * 2;

  hipMemsetAsync(deg, 0, (size_t)n * 4, stream);

  int nwaves = (n + 15) / 16;
  int nbc   = (nwaves + 3) / 4;
  int nb_e4 = (e + 1023) / 1024;
  int nb_s  = (n + 1023) / 1024;

  klayout <<<1, 256, 0, stream>>>(W, atts, attd, w1, w2, Wb, Zb, V1b, V2b);
  k1m     <<<nbc + nb_e4, 256, 0, stream>>>(x, Wb, Zb, ei, xq, asc, a_d, deg, n, e, nbc);
  kscanA  <<<nb_s, 256, 0, stream>>>(deg, bsum, n);
  kscanB  <<<1, 1024, 0, stream>>>(bsum, nb_s);
  kscanC  <<<nb_s, 256, 0, stream>>>(deg, bsum, offs, cursor, n);
  kscatter<<<nb_e4, 256, 0, stream>>>(ei, e, cursor, csr);
  kagg    <<<(n + 3) / 4, 256, 0, stream>>>(csr, offs, deg, (const float2*)asc, a_d,
                                            xq, og, n);
  k5m     <<<nbc, 256, 0, stream>>>(og, x, bg, V1b, V2b, b1, b2, g1, be1, g2, be2,
                                    (float*)d_out, n);
}

// Round 6
// 336.353 us; speedup vs baseline: 12.8579x; 1.0804x over previous
//
#include <hip/hip_runtime.h>
#include <stdint.h>

#define HH 8
#define CC 32
#define HC 256   // H*C
#define FF 128
#define NEG 0.2f
#define LNEPS 1e-5f

typedef __attribute__((ext_vector_type(8))) short bf16x8;
typedef __attribute__((ext_vector_type(4))) float f32x4;
typedef unsigned short u16;

// ---------- helpers ----------
__device__ inline unsigned bf16r(float f) {           // round-to-nearest-even bf16
  unsigned u = __float_as_uint(f);
  return (u + 0x7fffu + ((u >> 16) & 1u)) >> 16;
}
__device__ inline float bflo(unsigned w) { return __uint_as_float(w << 16); }
__device__ inline float bfhi(unsigned w) { return __uint_as_float(w & 0xffff0000u); }
__device__ inline float leaky(float v) { return v >= 0.f ? v : NEG * v; }
// byte extract -> float (v_cvt_f32_ubyte0..3)
__device__ inline float ub0(unsigned w) { return (float)(w & 0xffu); }
__device__ inline float ub1(unsigned w) { return (float)((w >> 8) & 0xffu); }
__device__ inline float ub2(unsigned w) { return (float)((w >> 16) & 0xffu); }
__device__ inline float ub3(unsigned w) { return (float)(w >> 24); }

// ---------- KLAYOUT: repack weights into MFMA B-fragment layout (bf16) ----------
// B-frag (16x16x32): lane l supplies B[8*(l>>4)+j][l&15], j=0..7 contiguous.
__global__ __launch_bounds__(256) void klayout(
    const float* __restrict__ W, const float* __restrict__ atts,
    const float* __restrict__ attd, const float* __restrict__ w1,
    const float* __restrict__ w2,
    u16* __restrict__ Wb, u16* __restrict__ Zb,
    u16* __restrict__ V1b, u16* __restrict__ V2b)
{
  int t = threadIdx.x;
  for (int i = t; i < 16 * 512; i += 256) {        // Wb: W_gat [32,256]
    int j = i & 7, l = (i >> 3) & 63, nb = i >> 9;
    int k = 8 * (l >> 4) + j, c = 16 * nb + (l & 15);
    Wb[i] = (u16)bf16r(W[k * HC + c]);
  }
  for (int i = t; i < 8 * 512; i += 256) {         // Zb: [256,16] = [atts|attd] blockdiag
    int j = i & 7, l = (i >> 3) & 63, kb = i >> 9;
    int k = 32 * kb + 8 * (l >> 4) + j;            // channel 0..255
    int tc = l & 15;
    float v = 0.f;
    if (tc < 8)  { if ((k >> 5) == tc)     v = atts[tc * 32 + (k & 31)]; }
    else         { if ((k >> 5) == tc - 8) v = attd[(tc - 8) * 32 + (k & 31)]; }
    Zb[i] = (u16)bf16r(v);
  }
  for (int i = t; i < 8 * 512; i += 256) {         // V1b: w1 [32,128]
    int j = i & 7, l = (i >> 3) & 63, nb = i >> 9;
    int k = 8 * (l >> 4) + j, c = 16 * nb + (l & 15);
    V1b[i] = (u16)bf16r(w1[k * FF + c]);
  }
  for (int i = t; i < 8 * 512; i += 256) {         // V2b: w2 [128,32]
    int j = i & 7, l = (i >> 3) & 63, kn = i >> 9;
    int kb = kn >> 1, nb2 = kn & 1;
    int k = 32 * kb + 8 * (l >> 4) + j, c = 16 * nb2 + (l & 15);
    V2b[i] = (u16)bf16r(w2[k * CC + c]);
  }
}

// ---------- K1M: MFMA xp=x@W -> int8 rows + per-(node,head) scale + a dots + hist ----------
__global__ __launch_bounds__(256) void k1m(
    const float* __restrict__ x, const u16* __restrict__ Wb,
    const u16* __restrict__ Zb, const int* __restrict__ ei,
    signed char* __restrict__ xq, float* __restrict__ asc,
    float* __restrict__ a_d, int* __restrict__ deg, int n, int e, int nbc)
{
  if ((int)blockIdx.x >= nbc) {                    // histogram role
    int i = ((int)blockIdx.x - nbc) * 1024 + (int)threadIdx.x * 4;
    if (i >= e) return;
    const int* dst = ei + e;
    if (i + 3 < e) {
      int4 d4 = *(const int4*)(dst + i);
      atomicAdd(&deg[d4.x], 1); atomicAdd(&deg[d4.y], 1);
      atomicAdd(&deg[d4.z], 1); atomicAdd(&deg[d4.w], 1);
    } else {
      for (int k = 0; k < 4 && i + k < e; ++k) atomicAdd(&deg[dst[i + k]], 1);
    }
    return;
  }
  __shared__ u16 lt[4][16 * 264];                  // per-wave [16 rows][264 halfs]
  __shared__ float lsc[4][16][8];                  // per-wave rinv = 127/rowmax
  int wid = threadIdx.x >> 6, lane = threadIdx.x & 63;
  int q = lane & 15, g = lane >> 4;
  long node0 = (long)((int)blockIdx.x * 4 + wid) * 16;
  if (node0 + 16 > n) node0 = n - 16;              // overlap tail: duplicate identical writes
  u16* L = lt[wid];

  // A-frag: x[node0+q][8g..8g+7] -> bf16
  const float* xr = x + (node0 + q) * CC + 8 * g;
  float4 xa = *(const float4*)xr, xb = *(const float4*)(xr + 4);
  bf16x8 af;
  af[0] = (short)bf16r(xa.x); af[1] = (short)bf16r(xa.y);
  af[2] = (short)bf16r(xa.z); af[3] = (short)bf16r(xa.w);
  af[4] = (short)bf16r(xb.x); af[5] = (short)bf16r(xb.y);
  af[6] = (short)bf16r(xb.z); af[7] = (short)bf16r(xb.w);

#pragma unroll
  for (int nb = 0; nb < 16; ++nb) {
    bf16x8 bf = *(const bf16x8*)(Wb + nb * 512 + lane * 8);
    f32x4 acc = {0.f, 0.f, 0.f, 0.f};
    acc = __builtin_amdgcn_mfma_f32_16x16x32_bf16(af, bf, acc, 0, 0, 0);
    int col = 16 * nb + q;
#pragma unroll
    for (int r = 0; r < 4; ++r)
      L[(4 * g + r) * 264 + col] = (u16)bf16r(acc[r]);
  }
  __syncthreads();

  // a_src/a_dst: [16 nodes,256] x [256,16] via 8 chained mfma
  f32x4 az = {0.f, 0.f, 0.f, 0.f};
#pragma unroll
  for (int kb = 0; kb < 8; ++kb) {
    bf16x8 a2 = *(const bf16x8*)(L + q * 264 + kb * 32 + g * 8);
    bf16x8 zb = *(const bf16x8*)(Zb + kb * 512 + lane * 8);
    az = __builtin_amdgcn_mfma_f32_16x16x32_bf16(a2, zb, az, 0, 0, 0);
  }
  int hq = q & 7;
  if (q < 8) {                                     // a_src -> asc[.x]
#pragma unroll
    for (int r = 0; r < 4; ++r)
      asc[((node0 + 4 * g + r) * HH + hq) * 2] = az[r];
  } else {                                         // a_dst
#pragma unroll
    for (int r = 0; r < 4; ++r)
      a_d[(node0 + 4 * g + r) * HH + hq] = az[r];
  }

  // per-(row,head) absmax -> scale (asc[.y]) + rinv (LDS)
#pragma unroll
  for (int t2 = 0; t2 < 2; ++t2) {
    int task = t2 * 64 + lane;                     // 128 tasks
    int r = task >> 3, h = task & 7;
    const unsigned* p = (const unsigned*)(L + r * 264 + h * 32);
    float mx = 0.f;
#pragma unroll
    for (int i = 0; i < 16; ++i) {
      unsigned w = p[i];
      mx = fmaxf(mx, fmaxf(fabsf(bflo(w)), fabsf(bfhi(w))));
    }
    float scale = mx * (1.f / 127.f);
    float rinv = (mx > 0.f) ? 127.f / mx : 0.f;
    asc[((node0 + r) * HH + h) * 2 + 1] = scale;
    lsc[wid][r][h] = rinv;
  }
  __syncthreads();

  // int8 encode + store: 16 rows x 64 dwords, 16 dwords per lane
#pragma unroll
  for (int i = 0; i < 16; ++i) {
    int d = i * 64 + lane;
    int r = d >> 6, c = d & 63;                    // c: dword within row
    int h = c >> 3;
    float rv = lsc[wid][r][h];
    const unsigned* p = (const unsigned*)(L + r * 264) + (c << 1);
    unsigned w0 = p[0], w1 = p[1];
    int q0 = __float2int_rn(bflo(w0) * rv);
    int q1 = __float2int_rn(bfhi(w0) * rv);
    int q2 = __float2int_rn(bflo(w1) * rv);
    int q3 = __float2int_rn(bfhi(w1) * rv);
    q0 = min(max(q0, -127), 127) + 128;
    q1 = min(max(q1, -127), 127) + 128;
    q2 = min(max(q2, -127), 127) + 128;
    q3 = min(max(q3, -127), 127) + 128;
    unsigned pk = (unsigned)q0 | ((unsigned)q1 << 8) |
                  ((unsigned)q2 << 16) | ((unsigned)q3 << 24);
    *(unsigned*)(xq + (node0 + r) * HC + c * 4) = pk;
  }
}

// ---------- scan phase A ----------
__global__ __launch_bounds__(256) void kscanA(const int* __restrict__ deg,
                                              int* __restrict__ bsum, int n)
{
  __shared__ int ws[4];
  int t = threadIdx.x;
  int i = (int)blockIdx.x * 1024 + t * 4;
  int4 v = make_int4(0, 0, 0, 0);
  if (i + 3 < n) v = *(const int4*)(deg + i);
  else {
    if (i     < n) v.x = deg[i];
    if (i + 1 < n) v.y = deg[i + 1];
    if (i + 2 < n) v.z = deg[i + 2];
    if (i + 3 < n) v.w = deg[i + 3];
  }
  int s = v.x + v.y + v.z + v.w;
#pragma unroll
  for (int mask = 1; mask < 64; mask <<= 1) s += __shfl_xor(s, mask);
  if ((t & 63) == 0) ws[t >> 6] = s;
  __syncthreads();
  if (t == 0) bsum[blockIdx.x] = ws[0] + ws[1] + ws[2] + ws[3];
}

// ---------- scan phase B ----------
__global__ __launch_bounds__(1024) void kscanB(int* __restrict__ bsum, int nb)
{
  __shared__ int wsum[16];
  int t = threadIdx.x, lane = t & 63, wid = t >> 6;
  int v = (t < nb) ? bsum[t] : 0;
  int s = v;
#pragma unroll
  for (int d = 1; d < 64; d <<= 1) { int tt = __shfl_up(s, d); if (lane >= d) s += tt; }
  if (lane == 63) wsum[wid] = s;
  __syncthreads();
  if (wid == 0) {
    int w = (lane < 16) ? wsum[lane] : 0;
#pragma unroll
    for (int d = 1; d < 16; d <<= 1) { int tt = __shfl_up(w, d); if (lane >= d) w += tt; }
    if (lane < 16) wsum[lane] = w;
  }
  __syncthreads();
  int excl = s - v + ((wid > 0) ? wsum[wid - 1] : 0);
  if (t < nb) bsum[t] = excl;
}

// ---------- scan phase C ----------
__global__ __launch_bounds__(256) void kscanC(const int* __restrict__ deg,
                                              const int* __restrict__ bsum,
                                              int* __restrict__ offs,
                                              int* __restrict__ cursor, int n)
{
  __shared__ int ws[4];
  int t = threadIdx.x, lane = t & 63, wid = t >> 6;
  int i = (int)blockIdx.x * 1024 + t * 4;
  int4 v = make_int4(0, 0, 0, 0);
  if (i + 3 < n) v = *(const int4*)(deg + i);
  else {
    if (i     < n) v.x = deg[i];
    if (i + 1 < n) v.y = deg[i + 1];
    if (i + 2 < n) v.z = deg[i + 2];
    if (i + 3 < n) v.w = deg[i + 3];
  }
  int tsum = v.x + v.y + v.z + v.w;
  int s = tsum;
#pragma unroll
  for (int d = 1; d < 64; d <<= 1) { int tt = __shfl_up(s, d); if (lane >= d) s += tt; }
  if (lane == 63) ws[wid] = s;
  __syncthreads();
  if (t == 0) {
    int a = ws[0]; ws[0] = 0;
    int b = ws[1]; ws[1] = a; a += b;
    int c = ws[2]; ws[2] = a; a += c;
    ws[3] = a;
  }
  __syncthreads();
  int base = bsum[blockIdx.x] + ws[wid] + (s - tsum);
  if (i     < n) { offs[i]     = base; cursor[i]     = base; } base += v.x;
  if (i + 1 < n) { offs[i + 1] = base; cursor[i + 1] = base; } base += v.y;
  if (i + 2 < n) { offs[i + 2] = base; cursor[i + 2] = base; } base += v.z;
  if (i + 3 < n) { offs[i + 3] = base; cursor[i + 3] = base; }
}

// ---------- CSR scatter: dst-octant passes for L2-resident writes ----------
// oct = blockIdx&7 -> each octant's writes span ~csr_bytes/8 (L2-resident);
// the edge stream is re-read once per octant (coalesced, cheap).
__global__ __launch_bounds__(256) void kscatter(const int* __restrict__ ei, int e,
                                                int* __restrict__ cursor,
                                                int* __restrict__ csr, int n)
{
  int oct = (int)blockIdx.x & 7;
  int nsub = (int)gridDim.x >> 3;
  int sub = (int)blockIdx.x >> 3;
  int nper = (n + 7) >> 3;
  int lo = oct * nper, hi = lo + nper;
  int stride = nsub << 10;                     // nsub * 256 threads * 4 edges
  const int* dst = ei + e;
  for (int i = (sub * 256 + (int)threadIdx.x) * 4; i < e; i += stride) {
    if (i + 3 < e) {
      int4 d4 = *(const int4*)(dst + i);
      int4 s4 = *(const int4*)(ei + i);
      if (d4.x >= lo && d4.x < hi) csr[atomicAdd(&cursor[d4.x], 1)] = s4.x;
      if (d4.y >= lo && d4.y < hi) csr[atomicAdd(&cursor[d4.y], 1)] = s4.y;
      if (d4.z >= lo && d4.z < hi) csr[atomicAdd(&cursor[d4.z], 1)] = s4.z;
      if (d4.w >= lo && d4.w < hi) csr[atomicAdd(&cursor[d4.w], 1)] = s4.w;
    } else {
      for (int k = 0; k < 4 && i + k < e; ++k) {
        int d = dst[i + k];
        if (d >= lo && d < hi) csr[atomicAdd(&cursor[d], 1)] = ei[i + k];
      }
    }
  }
}

// ---------- KAGG: wave-per-node, chunk-of-8 online softmax + int8 value gather ----------
// phase-A layout: eg=lane>>3 (edge in chunk), ha=lane&7 (head)
// phase-B layout: hb=lane>>3 (head), (lane&7)*4 channels
__global__ __launch_bounds__(256) void kagg(
    const int* __restrict__ csr, const int* __restrict__ offs,
    const int* __restrict__ deg,
    const float2* __restrict__ asc, const float* __restrict__ a_d,
    const signed char* __restrict__ xq, float* __restrict__ og, int n)
{
  int lane = threadIdx.x & 63;
  int node = (int)blockIdx.x * 4 + (threadIdx.x >> 6);
  if (node >= n) return;
  int eg = lane >> 3, ha = lane & 7;
  int hb = eg;                         // head in B layout
  int boff = hb * 32 + (lane & 7) * 4; // byte offset in 256B row

  int start = offs[node];
  int dg = deg[node];
  float ad_a  = a_d[(size_t)node * HH + ha];
  float aself = leaky(asc[(size_t)node * HH + ha].x + ad_a);
  float m = aself, dn = 1.f;
  float acc0 = 0.f, acc1 = 0.f, acc2 = 0.f, acc3 = 0.f, osum = 0.f;

  for (int j0 = 0; j0 < dg; j0 += 8) {
    int rem = dg - j0;
    int cnt = rem < 8 ? rem : 8;
    int idx = j0 + eg;
    int srcl = 0; float al = -3.0e38f; float sc = 0.f;
    if (idx < dg) {
      srcl = csr[start + idx];
      float2 v = asc[(size_t)srcl * HH + ha];
      al = leaky(v.x + ad_a);
      sc = v.y;
    }
    float cm = fmaxf(al, __shfl_xor(al, 8));
    cm = fmaxf(cm, __shfl_xor(cm, 16));
    cm = fmaxf(cm, __shfl_xor(cm, 32));
    float mn = fmaxf(m, cm);
    float scale = __expf(m - mn);
    m = mn;
    float p = (idx < dg) ? __expf(al - m) : 0.f;
    float ps = p + __shfl_xor(p, 8);
    ps += __shfl_xor(ps, 16);
    ps += __shfl_xor(ps, 32);
    dn = dn * scale + ps;
    float wsrc = p * sc;               // A-layout weight: one shfl instead of two
    float sb = __shfl(scale, hb);
    acc0 *= sb; acc1 *= sb; acc2 *= sb; acc3 *= sb; osum *= sb;
    if (cnt == 8) {
#pragma unroll
      for (int j = 0; j < 8; ++j) {
        float wt = __shfl(wsrc, (j << 3) + hb);
        int s = __shfl(srcl, j << 3);
        unsigned w = *(const unsigned*)(xq + ((size_t)s << 8) + boff);
        osum += wt;
        acc0 = fmaf(ub0(w), wt, acc0);
        acc1 = fmaf(ub1(w), wt, acc1);
        acc2 = fmaf(ub2(w), wt, acc2);
        acc3 = fmaf(ub3(w), wt, acc3);
      }
    } else {
      for (int j = 0; j < cnt; ++j) {
        float wt = __shfl(wsrc, (j << 3) + hb);
        int s = __shfl(srcl, j << 3);
        unsigned w = *(const unsigned*)(xq + ((size_t)s << 8) + boff);
        osum += wt;
        acc0 = fmaf(ub0(w), wt, acc0);
        acc1 = fmaf(ub1(w), wt, acc1);
        acc2 = fmaf(ub2(w), wt, acc2);
        acc3 = fmaf(ub3(w), wt, acc3);
      }
    }
  }
  // self loop
  float sw  = __shfl(__expf(aself - m), hb);
  float dnb = __shfl(dn, hb);
  {
    float ssc = asc[(size_t)node * HH + hb].y;
    float wt = sw * ssc;
    unsigned w = *(const unsigned*)(xq + ((size_t)node << 8) + boff);
    osum += wt;
    acc0 = fmaf(ub0(w), wt, acc0);
    acc1 = fmaf(ub1(w), wt, acc1);
    acc2 = fmaf(ub2(w), wt, acc2);
    acc3 = fmaf(ub3(w), wt, acc3);
  }
  float corr = -128.f * osum;
  float inv = 0.125f / (dnb + 1e-16f);
  acc0 = (acc0 + corr) * inv;
  acc1 = (acc1 + corr) * inv;
  acc2 = (acc2 + corr) * inv;
  acc3 = (acc3 + corr) * inv;
#pragma unroll
  for (int mask = 8; mask < 64; mask <<= 1) {
    acc0 += __shfl_xor(acc0, mask);
    acc1 += __shfl_xor(acc1, mask);
    acc2 += __shfl_xor(acc2, mask);
    acc3 += __shfl_xor(acc3, mask);
  }
  if (lane < 8) {
    *(float4*)(og + (size_t)node * CC + lane * 4) =
      make_float4(acc0, acc1, acc2, acc3);
  }
}

// ---------- K5M: MFMA tail — LN1 + FFN(mfma) + LN2 ----------
__global__ __launch_bounds__(256) void k5m(
    const float* __restrict__ og, const float* __restrict__ x,
    const float* __restrict__ bg,
    const u16* __restrict__ V1b, const u16* __restrict__ V2b,
    const float* __restrict__ b1, const float* __restrict__ b2,
    const float* __restrict__ g1, const float* __restrict__ be1,
    const float* __restrict__ g2, const float* __restrict__ be2,
    float* __restrict__ out, int n)
{
  __shared__ u16   lh[4][16 * 40];                 // h bf16 [16][32] pad 40
  __shared__ u16   lf[4][16 * 136];                // f bf16 [16][128] pad 136
  __shared__ float lo[4][16 * 36];                 // fp32 [16][32] pad 36
  int wid = threadIdx.x >> 6, lane = threadIdx.x & 63;
  int q = lane & 15, g = lane >> 4;
  long node0 = (long)((int)blockIdx.x * 4 + wid) * 16;
  if (node0 + 16 > n) node0 = n - 16;
  u16* LH = lh[wid]; u16* LF = lf[wid]; float* LO = lo[wid];

  {
    int row = lane >> 2, off = (lane & 3) * 8;
    const float* o8 = og + (node0 + row) * CC + off;
    const float* x8 = x  + (node0 + row) * CC + off;
    float4 a0 = *(const float4*)o8, a1 = *(const float4*)(o8 + 4);
    float4 c0 = *(const float4*)x8, c1 = *(const float4*)(x8 + 4);
    float4 bg0 = *(const float4*)(bg + off), bg1 = *(const float4*)(bg + off + 4);
    float4 s0 = make_float4(a0.x + c0.x + bg0.x, a0.y + c0.y + bg0.y,
                            a0.z + c0.z + bg0.z, a0.w + c0.w + bg0.w);
    float4 s1 = make_float4(a1.x + c1.x + bg1.x, a1.y + c1.y + bg1.y,
                            a1.z + c1.z + bg1.z, a1.w + c1.w + bg1.w);
    *(float4*)(LO + row * 36 + off)     = s0;
    *(float4*)(LO + row * 36 + off + 4) = s1;
  }
  __syncthreads();

  float hv[32];
  if (lane < 16) {
#pragma unroll
    for (int i = 0; i < 8; ++i) {
      float4 t = *(const float4*)(LO + q * 36 + i * 4);
      hv[4*i] = t.x; hv[4*i+1] = t.y; hv[4*i+2] = t.z; hv[4*i+3] = t.w;
    }
    float mu = 0.f;
#pragma unroll
    for (int c = 0; c < 32; ++c) mu += hv[c];
    mu *= (1.f / 32.f);
    float var = 0.f;
#pragma unroll
    for (int c = 0; c < 32; ++c) { float t = hv[c] - mu; var = fmaf(t, t, var); }
    float rs = rsqrtf(var * (1.f / 32.f) + LNEPS);
#pragma unroll
    for (int c = 0; c < 32; ++c) hv[c] = (hv[c] - mu) * rs * g1[c] + be1[c];
    uint* dst = (uint*)(LH + q * 40);
#pragma unroll
    for (int i = 0; i < 16; ++i)
      dst[i] = bf16r(hv[2*i]) | (bf16r(hv[2*i+1]) << 16);
  }
  __syncthreads();

  bf16x8 ah = *(const bf16x8*)(LH + q * 40 + g * 8);
#pragma unroll
  for (int nb = 0; nb < 8; ++nb) {
    bf16x8 v1 = *(const bf16x8*)(V1b + nb * 512 + lane * 8);
    f32x4 acc = {0.f, 0.f, 0.f, 0.f};
    acc = __builtin_amdgcn_mfma_f32_16x16x32_bf16(ah, v1, acc, 0, 0, 0);
    int col = 16 * nb + q;
    float bias = b1[col];
#pragma unroll
    for (int r = 0; r < 4; ++r) {
      float f = fmaxf(acc[r] + bias, 0.f);
      LF[(4 * g + r) * 136 + col] = (u16)bf16r(f);
    }
  }
  __syncthreads();

  f32x4 a20 = {0.f, 0.f, 0.f, 0.f}, a21 = {0.f, 0.f, 0.f, 0.f};
#pragma unroll
  for (int kb = 0; kb < 4; ++kb) {
    bf16x8 af2 = *(const bf16x8*)(LF + q * 136 + kb * 32 + g * 8);
    bf16x8 v20 = *(const bf16x8*)(V2b + (kb * 2 + 0) * 512 + lane * 8);
    bf16x8 v21 = *(const bf16x8*)(V2b + (kb * 2 + 1) * 512 + lane * 8);
    a20 = __builtin_amdgcn_mfma_f32_16x16x32_bf16(af2, v20, a20, 0, 0, 0);
    a21 = __builtin_amdgcn_mfma_f32_16x16x32_bf16(af2, v21, a21, 0, 0, 0);
  }
  __syncthreads();
#pragma unroll
  for (int r = 0; r < 4; ++r) {
    LO[(4 * g + r) * 36 + q]      = a20[r];
    LO[(4 * g + r) * 36 + 16 + q] = a21[r];
  }
  __syncthreads();

  if (lane < 16) {
    float ov[32];
#pragma unroll
    for (int i = 0; i < 8; ++i) {
      float4 t = *(const float4*)(LO + q * 36 + i * 4);
      ov[4*i] = t.x; ov[4*i+1] = t.y; ov[4*i+2] = t.z; ov[4*i+3] = t.w;
    }
#pragma unroll
    for (int c = 0; c < 32; ++c) ov[c] += b2[c] + hv[c];
    float mu2 = 0.f;
#pragma unroll
    for (int c = 0; c < 32; ++c) mu2 += ov[c];
    mu2 *= (1.f / 32.f);
    float var2 = 0.f;
#pragma unroll
    for (int c = 0; c < 32; ++c) { float t = ov[c] - mu2; var2 = fmaf(t, t, var2); }
    float rs2 = rsqrtf(var2 * (1.f / 32.f) + LNEPS);
    float* op = out + (node0 + q) * CC;
#pragma unroll
    for (int i = 0; i < 8; ++i) {
      float4 o;
      o.x = (ov[4*i]   - mu2) * rs2 * g2[4*i]   + be2[4*i];
      o.y = (ov[4*i+1] - mu2) * rs2 * g2[4*i+1] + be2[4*i+1];
      o.z = (ov[4*i+2] - mu2) * rs2 * g2[4*i+2] + be2[4*i+2];
      o.w = (ov[4*i+3] - mu2) * rs2 * g2[4*i+3] + be2[4*i+3];
      *(float4*)(op + i * 4) = o;
    }
  }
}

// ---------- launch ----------
extern "C" void kernel_launch(void* const* d_in, const int* in_sizes, int n_in,
                              void* d_out, int out_size, void* d_ws, size_t ws_size,
                              hipStream_t stream)
{
  const float* x    = (const float*)d_in[0];
  const int*   ei   = (const int*)d_in[1];
  const float* W    = (const float*)d_in[2];
  const float* atts = (const float*)d_in[3];
  const float* attd = (const float*)d_in[4];
  const float* bg   = (const float*)d_in[5];
  const float* w1   = (const float*)d_in[6];
  const float* b1   = (const float*)d_in[7];
  const float* w2   = (const float*)d_in[8];
  const float* b2   = (const float*)d_in[9];
  const float* g1   = (const float*)d_in[10];
  const float* be1  = (const float*)d_in[11];
  const float* g2   = (const float*)d_in[12];
  const float* be2  = (const float*)d_in[13];

  int n = in_sizes[0] / CC;
  int e = in_sizes[1] / 2;

  uint8_t* ws = (uint8_t*)d_ws;
  size_t o = 0;
  signed char* xq = (signed char*)(ws + o); o += (size_t)n * HC; o = (o + 255) & ~(size_t)255;
  float* asc = (float*)(ws + o); o += (size_t)n * HH * 8;   // float2 per (node,head)
  float* a_d = (float*)(ws + o); o += (size_t)n * HH * 4;
  float* og  = (float*)(ws + o); o += (size_t)n * CC * 4;
  int* deg    = (int*)(ws + o); o += (size_t)n * 4;
  int* offs   = (int*)(ws + o); o += (size_t)n * 4;
  int* cursor = (int*)(ws + o); o += (size_t)n * 4;
  int* csr    = (int*)(ws + o); o += (size_t)e * 4;
  int* bsum   = (int*)(ws + o); o += 4096;
  u16* Wb  = (u16*)(ws + o); o += 16 * 512 * 2;
  u16* Zb  = (u16*)(ws + o); o += 8 * 512 * 2;
  u16* V1b = (u16*)(ws + o); o += 8 * 512 * 2;
  u16* V2b = (u16*)(ws + o); o += 8 * 512 * 2;

  hipMemsetAsync(deg, 0, (size_t)n * 4, stream);

  int nwaves = (n + 15) / 16;
  int nbc   = (nwaves + 3) / 4;
  int nb_e4 = (e + 1023) / 1024;
  int nb_s  = (n + 1023) / 1024;

  klayout <<<1, 256, 0, stream>>>(W, atts, attd, w1, w2, Wb, Zb, V1b, V2b);
  k1m     <<<nbc + nb_e4, 256, 0, stream>>>(x, Wb, Zb, ei, xq, asc, a_d, deg, n, e, nbc);
  kscanA  <<<nb_s, 256, 0, stream>>>(deg, bsum, n);
  kscanB  <<<1, 1024, 0, stream>>>(bsum, nb_s);
  kscanC  <<<nb_s, 256, 0, stream>>>(deg, bsum, offs, cursor, n);
  kscatter<<<512, 256, 0, stream>>>(ei, e, cursor, csr, n);
  kagg    <<<(n + 3) / 4, 256, 0, stream>>>(csr, offs, deg, (const float2*)asc, a_d,
                                            xq, og, n);
  k5m     <<<nbc, 256, 0, stream>>>(og, x, bg, V1b, V2b, b1, b2, g1, be1, g2, be2,
                                    (float*)d_out, n);
}

// Round 9
// 315.665 us; speedup vs baseline: 13.7006x; 1.0655x over previous
//
#include <hip/hip_runtime.h>
#include <hip/hip_fp16.h>
#include <stdint.h>

#define HH 8
#define CC 32
#define HC 256   // H*C
#define FF 128
#define NEG 0.2f
#define LNEPS 1e-5f

typedef __attribute__((ext_vector_type(8))) short bf16x8;
typedef __attribute__((ext_vector_type(4))) float f32x4;
typedef unsigned short u16;

// ---------- helpers ----------
__device__ inline unsigned bf16r(float f) {           // round-to-nearest-even bf16
  unsigned u = __float_as_uint(f);
  return (u + 0x7fffu + ((u >> 16) & 1u)) >> 16;
}
__device__ inline float bflo(unsigned w) { return __uint_as_float(w << 16); }
__device__ inline float bfhi(unsigned w) { return __uint_as_float(w & 0xffff0000u); }
__device__ inline float leaky(float v) { return v >= 0.f ? v : NEG * v; }
__device__ inline float h2f(unsigned hbits) {
  return __half2float(__ushort_as_half((unsigned short)hbits));
}
__device__ inline u16 f2h(float f) {
  return __half_as_ushort(__float2half(f));
}
// byte extract -> float (v_cvt_f32_ubyte0..3)
__device__ inline float ub0(unsigned w) { return (float)(w & 0xffu); }
__device__ inline float ub1(unsigned w) { return (float)((w >> 8) & 0xffu); }
__device__ inline float ub2(unsigned w) { return (float)((w >> 16) & 0xffu); }
__device__ inline float ub3(unsigned w) { return (float)(w >> 24); }

// ---------- KLAYOUT: repack weights into MFMA B-fragment layout (bf16) ----------
__global__ __launch_bounds__(256) void klayout(
    const float* __restrict__ W, const float* __restrict__ atts,
    const float* __restrict__ attd, const float* __restrict__ w1,
    const float* __restrict__ w2,
    u16* __restrict__ Wb, u16* __restrict__ Zb,
    u16* __restrict__ V1b, u16* __restrict__ V2b)
{
  int t = threadIdx.x;
  for (int i = t; i < 16 * 512; i += 256) {        // Wb: W_gat [32,256]
    int j = i & 7, l = (i >> 3) & 63, nb = i >> 9;
    int k = 8 * (l >> 4) + j, c = 16 * nb + (l & 15);
    Wb[i] = (u16)bf16r(W[k * HC + c]);
  }
  for (int i = t; i < 8 * 512; i += 256) {         // Zb: [256,16] = [atts|attd] blockdiag
    int j = i & 7, l = (i >> 3) & 63, kb = i >> 9;
    int k = 32 * kb + 8 * (l >> 4) + j;
    int tc = l & 15;
    float v = 0.f;
    if (tc < 8)  { if ((k >> 5) == tc)     v = atts[tc * 32 + (k & 31)]; }
    else         { if ((k >> 5) == tc - 8) v = attd[(tc - 8) * 32 + (k & 31)]; }
    Zb[i] = (u16)bf16r(v);
  }
  for (int i = t; i < 8 * 512; i += 256) {         // V1b: w1 [32,128]
    int j = i & 7, l = (i >> 3) & 63, nb = i >> 9;
    int k = 8 * (l >> 4) + j, c = 16 * nb + (l & 15);
    V1b[i] = (u16)bf16r(w1[k * FF + c]);
  }
  for (int i = t; i < 8 * 512; i += 256) {         // V2b: w2 [128,32]
    int j = i & 7, l = (i >> 3) & 63, kn = i >> 9;
    int kb = kn >> 1, nb2 = kn & 1;
    int k = 32 * kb + 8 * (l >> 4) + j, c = 16 * nb2 + (l & 15);
    V2b[i] = (u16)bf16r(w2[k * CC + c]);
  }
}

// ---------- K1M: MFMA xp=x@W -> int8 rows + packed (bf16 a_src|fp16 scale) + a_dst
//             + fused histogram that ALSO emits per-edge rank (dst | rank<<17) ----------
__global__ __launch_bounds__(256) void k1m(
    const float* __restrict__ x, const u16* __restrict__ Wb,
    const u16* __restrict__ Zb, const int* __restrict__ ei,
    unsigned* __restrict__ xq8, unsigned* __restrict__ ascp,
    float* __restrict__ a_d, int* __restrict__ deg,
    unsigned* __restrict__ dstr, int n, int e, int nbc)
{
  if ((int)blockIdx.x >= nbc) {                    // histogram + rank role
    int i = ((int)blockIdx.x - nbc) * 1024 + (int)threadIdx.x * 4;
    if (i >= e) return;
    const int* dst = ei + e;
    if (i + 3 < e) {
      int4 d4 = *(const int4*)(dst + i);
      unsigned r0 = (unsigned)atomicAdd(&deg[d4.x], 1);
      unsigned r1 = (unsigned)atomicAdd(&deg[d4.y], 1);
      unsigned r2 = (unsigned)atomicAdd(&deg[d4.z], 1);
      unsigned r3 = (unsigned)atomicAdd(&deg[d4.w], 1);
      uint4 o;
      o.x = (unsigned)d4.x | (r0 << 17);
      o.y = (unsigned)d4.y | (r1 << 17);
      o.z = (unsigned)d4.z | (r2 << 17);
      o.w = (unsigned)d4.w | (r3 << 17);
      *(uint4*)(dstr + i) = o;
    } else {
      for (int k = 0; k < 4 && i + k < e; ++k) {
        int d = dst[i + k];
        unsigned r = (unsigned)atomicAdd(&deg[d], 1);
        dstr[i + k] = (unsigned)d | (r << 17);
      }
    }
    return;
  }
  __shared__ u16 lt[4][16 * 264];                  // per-wave [16 rows][264 halfs]
  __shared__ float lsc[4][16][8];                  // per-wave rinv = 127/rowmax
  int wid = threadIdx.x >> 6, lane = threadIdx.x & 63;
  int q = lane & 15, g = lane >> 4;
  long node0 = (long)((int)blockIdx.x * 4 + wid) * 16;
  if (node0 + 16 > n) node0 = n - 16;              // overlap tail: duplicate identical writes
  u16* L = lt[wid];

  // A-frag: x[node0+q][8g..8g+7] -> bf16
  const float* xr = x + (node0 + q) * CC + 8 * g;
  float4 xa = *(const float4*)xr, xb = *(const float4*)(xr + 4);
  bf16x8 af;
  af[0] = (short)bf16r(xa.x); af[1] = (short)bf16r(xa.y);
  af[2] = (short)bf16r(xa.z); af[3] = (short)bf16r(xa.w);
  af[4] = (short)bf16r(xb.x); af[5] = (short)bf16r(xb.y);
  af[6] = (short)bf16r(xb.z); af[7] = (short)bf16r(xb.w);

#pragma unroll
  for (int nb = 0; nb < 16; ++nb) {
    bf16x8 bf = *(const bf16x8*)(Wb + nb * 512 + lane * 8);
    f32x4 acc = {0.f, 0.f, 0.f, 0.f};
    acc = __builtin_amdgcn_mfma_f32_16x16x32_bf16(af, bf, acc, 0, 0, 0);
    int col = 16 * nb + q;
#pragma unroll
    for (int r = 0; r < 4; ++r)
      L[(4 * g + r) * 264 + col] = (u16)bf16r(acc[r]);
  }
  __syncthreads();

  // a_src/a_dst: [16 nodes,256] x [256,16] via 8 chained mfma
  f32x4 az = {0.f, 0.f, 0.f, 0.f};
#pragma unroll
  for (int kb = 0; kb < 8; ++kb) {
    bf16x8 a2 = *(const bf16x8*)(L + q * 264 + kb * 32 + g * 8);
    bf16x8 zb = *(const bf16x8*)(Zb + kb * 512 + lane * 8);
    az = __builtin_amdgcn_mfma_f32_16x16x32_bf16(a2, zb, az, 0, 0, 0);
  }
  int hq = q & 7;
  u16* ascp16 = (u16*)ascp;
  if (q < 8) {                                     // a_src -> ascp lo16 (bf16)
#pragma unroll
    for (int r = 0; r < 4; ++r)
      ascp16[((node0 + 4 * g + r) * HH + hq) * 2] = (u16)bf16r(az[r]);
  } else {                                         // a_dst (fp32)
#pragma unroll
    for (int r = 0; r < 4; ++r)
      a_d[(node0 + 4 * g + r) * HH + hq] = az[r];
  }

  // per-(row,head) absmax -> fp16 scale (ascp hi16) + rinv (LDS)
#pragma unroll
  for (int t2 = 0; t2 < 2; ++t2) {
    int task = t2 * 64 + lane;                     // 128 tasks
    int r = task >> 3, h = task & 7;
    const unsigned* p = (const unsigned*)(L + r * 264 + h * 32);
    float mx = 0.f;
#pragma unroll
    for (int i = 0; i < 16; ++i) {
      unsigned w = p[i];
      mx = fmaxf(mx, fmaxf(fabsf(bflo(w)), fabsf(bfhi(w))));
    }
    float rinv = (mx > 0.f) ? 127.f / mx : 0.f;
    ascp16[((node0 + r) * HH + h) * 2 + 1] = f2h(mx * (1.f / 127.f));
    lsc[wid][r][h] = rinv;
  }
  __syncthreads();

  // int8 encode + store: 16 rows x 64 dwords, 16 dwords per lane
#pragma unroll
  for (int i = 0; i < 16; ++i) {
    int d = i * 64 + lane;
    int r = d >> 6, c = d & 63;                    // c: dword within 256B row
    int h = c >> 3;
    float rv = lsc[wid][r][h];
    const unsigned* p = (const unsigned*)(L + r * 264) + (c << 1);
    unsigned w0 = p[0], w1 = p[1];
    int q0 = __float2int_rn(bflo(w0) * rv);
    int q1 = __float2int_rn(bfhi(w0) * rv);
    int q2 = __float2int_rn(bflo(w1) * rv);
    int q3 = __float2int_rn(bfhi(w1) * rv);
    q0 = min(max(q0, -127), 127) + 128;
    q1 = min(max(q1, -127), 127) + 128;
    q2 = min(max(q2, -127), 127) + 128;
    q3 = min(max(q3, -127), 127) + 128;
    unsigned pk = (unsigned)q0 | ((unsigned)q1 << 8) |
                  ((unsigned)q2 << 16) | ((unsigned)q3 << 24);
    xq8[(node0 + r) * 64 + c] = pk;
  }
}

// ---------- scan phase A ----------
__global__ __launch_bounds__(256) void kscanA(const int* __restrict__ deg,
                                              int* __restrict__ bsum, int n)
{
  __shared__ int ws[4];
  int t = threadIdx.x;
  int i = (int)blockIdx.x * 1024 + t * 4;
  int4 v = make_int4(0, 0, 0, 0);
  if (i + 3 < n) v = *(const int4*)(deg + i);
  else {
    if (i     < n) v.x = deg[i];
    if (i + 1 < n) v.y = deg[i + 1];
    if (i + 2 < n) v.z = deg[i + 2];
    if (i + 3 < n) v.w = deg[i + 3];
  }
  int s = v.x + v.y + v.z + v.w;
#pragma unroll
  for (int mask = 1; mask < 64; mask <<= 1) s += __shfl_xor(s, mask);
  if ((t & 63) == 0) ws[t >> 6] = s;
  __syncthreads();
  if (t == 0) bsum[blockIdx.x] = ws[0] + ws[1] + ws[2] + ws[3];
}

// ---------- scan phase B ----------
__global__ __launch_bounds__(1024) void kscanB(int* __restrict__ bsum, int nb)
{
  __shared__ int wsum[16];
  int t = threadIdx.x, lane = t & 63, wid = t >> 6;
  int v = (t < nb) ? bsum[t] : 0;
  int s = v;
#pragma unroll
  for (int d = 1; d < 64; d <<= 1) { int tt = __shfl_up(s, d); if (lane >= d) s += tt; }
  if (lane == 63) wsum[wid] = s;
  __syncthreads();
  if (wid == 0) {
    int w = (lane < 16) ? wsum[lane] : 0;
#pragma unroll
    for (int d = 1; d < 16; d <<= 1) { int tt = __shfl_up(w, d); if (lane >= d) w += tt; }
    if (lane < 16) wsum[lane] = w;
  }
  __syncthreads();
  int excl = s - v + ((wid > 0) ? wsum[wid - 1] : 0);
  if (t < nb) bsum[t] = excl;
}

// ---------- scan phase C ----------
__global__ __launch_bounds__(256) void kscanC(const int* __restrict__ deg,
                                              const int* __restrict__ bsum,
                                              int* __restrict__ offs, int n)
{
  __shared__ int ws[4];
  int t = threadIdx.x, lane = t & 63, wid = t >> 6;
  int i = (int)blockIdx.x * 1024 + t * 4;
  int4 v = make_int4(0, 0, 0, 0);
  if (i + 3 < n) v = *(const int4*)(deg + i);
  else {
    if (i     < n) v.x = deg[i];
    if (i + 1 < n) v.y = deg[i + 1];
    if (i + 2 < n) v.z = deg[i + 2];
    if (i + 3 < n) v.w = deg[i + 3];
  }
  int tsum = v.x + v.y + v.z + v.w;
  int s = tsum;
#pragma unroll
  for (int d = 1; d < 64; d <<= 1) { int tt = __shfl_up(s, d); if (lane >= d) s += tt; }
  if (lane == 63) ws[wid] = s;
  __syncthreads();
  if (t == 0) {
    int a = ws[0]; ws[0] = 0;
    int b = ws[1]; ws[1] = a; a += b;
    int c = ws[2]; ws[2] = a; a += c;
    ws[3] = a;
  }
  __syncthreads();
  int base = bsum[blockIdx.x] + ws[wid] + (s - tsum);
  if (i     < n) offs[i]     = base; base += v.x;
  if (i + 1 < n) offs[i + 1] = base; base += v.y;
  if (i + 2 < n) offs[i + 2] = base; base += v.z;
  if (i + 3 < n) offs[i + 3] = base;
}

// ---------- CSR scatter: rank-based, ATOMIC-FREE, dst-octant L2-local writes ----------
__global__ __launch_bounds__(256) void kscatter(
    const int* __restrict__ ei, const unsigned* __restrict__ dstr, int e,
    const int* __restrict__ offs, int* __restrict__ csr, int n)
{
  int oct = (int)blockIdx.x & 7;
  int nsub = (int)gridDim.x >> 3;
  int sub = (int)blockIdx.x >> 3;
  int nper = (n + 7) >> 3;
  int lo = oct * nper, hi = lo + nper;
  int stride = nsub << 10;
  for (int i = (sub * 256 + (int)threadIdx.x) * 4; i < e; i += stride) {
    if (i + 3 < e) {
      uint4 d4 = *(const uint4*)(dstr + i);
      int4 s4 = *(const int4*)(ei + i);
      int dx = d4.x & 0x1ffff, dy = d4.y & 0x1ffff,
          dz = d4.z & 0x1ffff, dw = d4.w & 0x1ffff;
      if (dx >= lo && dx < hi) csr[offs[dx] + (d4.x >> 17)] = s4.x;
      if (dy >= lo && dy < hi) csr[offs[dy] + (d4.y >> 17)] = s4.y;
      if (dz >= lo && dz < hi) csr[offs[dz] + (d4.z >> 17)] = s4.z;
      if (dw >= lo && dw < hi) csr[offs[dw] + (d4.w >> 17)] = s4.w;
    } else {
      for (int k = 0; k < 4 && i + k < e; ++k) {
        unsigned dv = dstr[i + k];
        int d = dv & 0x1ffff;
        if (d >= lo && d < hi) csr[offs[d] + (dv >> 17)] = ei[i + k];
      }
    }
  }
}

// ---------- KAGG: wave-per-node, chunk-of-8 online softmax + int8 value gather ----------
// phase-A layout: eg=lane>>3 (edge in chunk), ha=lane&7 (head)
// phase-B layout: hb=lane>>3 (head), (lane&7)*4 channels
__global__ __launch_bounds__(256) void kagg(
    const int* __restrict__ csr, const int* __restrict__ offs,
    const int* __restrict__ deg,
    const unsigned* __restrict__ ascp, const float* __restrict__ a_d,
    const unsigned* __restrict__ xq8, float* __restrict__ og, int n)
{
  int lane = threadIdx.x & 63;
  int node = (int)blockIdx.x * 4 + (threadIdx.x >> 6);
  if (node >= n) return;
  int eg = lane >> 3, ha = lane & 7;
  int hb = eg;                          // head in B layout
  int doff = hb * 8 + (lane & 7);       // dword index within 64-dword (256B) row

  int start = offs[node];
  int dg = deg[node];
  float ad_a  = a_d[(size_t)node * HH + ha];
  float aself = leaky(bflo(ascp[(size_t)node * HH + ha]) + ad_a);
  float m = aself, dn = 1.f;
  float acc0 = 0.f, acc1 = 0.f, acc2 = 0.f, acc3 = 0.f, osum = 0.f;

  for (int j0 = 0; j0 < dg; j0 += 8) {
    int rem = dg - j0;
    int cnt = rem < 8 ? rem : 8;
    int idx = j0 + eg;
    int srcl = 0; float al = -3.0e38f; float sc = 0.f;
    if (idx < dg) {
      srcl = csr[start + idx];
      unsigned av = ascp[(size_t)srcl * HH + ha];
      al = leaky(bflo(av) + ad_a);
      sc = h2f(av >> 16);
    }
    float cm = fmaxf(al, __shfl_xor(al, 8));
    cm = fmaxf(cm, __shfl_xor(cm, 16));
    cm = fmaxf(cm, __shfl_xor(cm, 32));
    float mn = fmaxf(m, cm);
    float scale = __expf(m - mn);
    m = mn;
    float p = (idx < dg) ? __expf(al - m) : 0.f;
    float ps = p + __shfl_xor(p, 8);
    ps += __shfl_xor(ps, 16);
    ps += __shfl_xor(ps, 32);
    dn = dn * scale + ps;
    float wsrc = p * sc;                // A-layout weight (includes value scale)
    float sb = __shfl(scale, hb);
    acc0 *= sb; acc1 *= sb; acc2 *= sb; acc3 *= sb; osum *= sb;
    if (cnt == 8) {
#pragma unroll
      for (int j = 0; j < 8; ++j) {
        float wt = __shfl(wsrc, (j << 3) + hb);
        int s = __shfl(srcl, j << 3);
        unsigned w = xq8[(size_t)s * 64 + doff];
        osum += wt;
        acc0 = fmaf(ub0(w), wt, acc0);
        acc1 = fmaf(ub1(w), wt, acc1);
        acc2 = fmaf(ub2(w), wt, acc2);
        acc3 = fmaf(ub3(w), wt, acc3);
      }
    } else {
      for (int j = 0; j < cnt; ++j) {
        float wt = __shfl(wsrc, (j << 3) + hb);
        int s = __shfl(srcl, j << 3);
        unsigned w = xq8[(size_t)s * 64 + doff];
        osum += wt;
        acc0 = fmaf(ub0(w), wt, acc0);
        acc1 = fmaf(ub1(w), wt, acc1);
        acc2 = fmaf(ub2(w), wt, acc2);
        acc3 = fmaf(ub3(w), wt, acc3);
      }
    }
  }
  // self loop
  float sw  = __shfl(__expf(aself - m), hb);
  float dnb = __shfl(dn, hb);
  {
    float ssc = h2f(ascp[(size_t)node * HH + hb] >> 16);
    float wt = sw * ssc;
    unsigned w = xq8[(size_t)node * 64 + doff];
    osum += wt;
    acc0 = fmaf(ub0(w), wt, acc0);
    acc1 = fmaf(ub1(w), wt, acc1);
    acc2 = fmaf(ub2(w), wt, acc2);
    acc3 = fmaf(ub3(w), wt, acc3);
  }
  float corr = -128.f * osum;
  float inv = 0.125f / (dnb + 1e-16f);
  acc0 = (acc0 + corr) * inv;
  acc1 = (acc1 + corr) * inv;
  acc2 = (acc2 + corr) * inv;
  acc3 = (acc3 + corr) * inv;
#pragma unroll
  for (int mask = 8; mask < 64; mask <<= 1) {
    acc0 += __shfl_xor(acc0, mask);
    acc1 += __shfl_xor(acc1, mask);
    acc2 += __shfl_xor(acc2, mask);
    acc3 += __shfl_xor(acc3, mask);
  }
  if (lane < 8) {
    *(float4*)(og + (size_t)node * CC + lane * 4) =
      make_float4(acc0, acc1, acc2, acc3);
  }
}

// ---------- K5M: MFMA tail — LN1 + FFN(mfma) + LN2 ----------
__global__ __launch_bounds__(256) void k5m(
    const float* __restrict__ og, const float* __restrict__ x,
    const float* __restrict__ bg,
    const u16* __restrict__ V1b, const u16* __restrict__ V2b,
    const float* __restrict__ b1, const float* __restrict__ b2,
    const float* __restrict__ g1, const float* __restrict__ be1,
    const float* __restrict__ g2, const float* __restrict__ be2,
    float* __restrict__ out, int n)
{
  __shared__ u16   lh[4][16 * 40];
  __shared__ u16   lf[4][16 * 136];
  __shared__ float lo[4][16 * 36];
  int wid = threadIdx.x >> 6, lane = threadIdx.x & 63;
  int q = lane & 15, g = lane >> 4;
  long node0 = (long)((int)blockIdx.x * 4 + wid) * 16;
  if (node0 + 16 > n) node0 = n - 16;
  u16* LH = lh[wid]; u16* LF = lf[wid]; float* LO = lo[wid];

  {
    int row = lane >> 2, off = (lane & 3) * 8;
    const float* o8 = og + (node0 + row) * CC + off;
    const float* x8 = x  + (node0 + row) * CC + off;
    float4 a0 = *(const float4*)o8, a1 = *(const float4*)(o8 + 4);
    float4 c0 = *(const float4*)x8, c1 = *(const float4*)(x8 + 4);
    float4 bg0 = *(const float4*)(bg + off), bg1 = *(const float4*)(bg + off + 4);
    float4 s0 = make_float4(a0.x + c0.x + bg0.x, a0.y + c0.y + bg0.y,
                            a0.z + c0.z + bg0.z, a0.w + c0.w + bg0.w);
    float4 s1 = make_float4(a1.x + c1.x + bg1.x, a1.y + c1.y + bg1.y,
                            a1.z + c1.z + bg1.z, a1.w + c1.w + bg1.w);
    *(float4*)(LO + row * 36 + off)     = s0;
    *(float4*)(LO + row * 36 + off + 4) = s1;
  }
  __syncthreads();

  float hv[32];
  if (lane < 16) {
#pragma unroll
    for (int i = 0; i < 8; ++i) {
      float4 t = *(const float4*)(LO + q * 36 + i * 4);
      hv[4*i] = t.x; hv[4*i+1] = t.y; hv[4*i+2] = t.z; hv[4*i+3] = t.w;
    }
    float mu = 0.f;
#pragma unroll
    for (int c = 0; c < 32; ++c) mu += hv[c];
    mu *= (1.f / 32.f);
    float var = 0.f;
#pragma unroll
    for (int c = 0; c < 32; ++c) { float t = hv[c] - mu; var = fmaf(t, t, var); }
    float rs = rsqrtf(var * (1.f / 32.f) + LNEPS);
#pragma unroll
    for (int c = 0; c < 32; ++c) hv[c] = (hv[c] - mu) * rs * g1[c] + be1[c];
    uint* dst = (uint*)(LH + q * 40);
#pragma unroll
    for (int i = 0; i < 16; ++i)
      dst[i] = bf16r(hv[2*i]) | (bf16r(hv[2*i+1]) << 16);
  }
  __syncthreads();

  bf16x8 ah = *(const bf16x8*)(LH + q * 40 + g * 8);
#pragma unroll
  for (int nb = 0; nb < 8; ++nb) {
    bf16x8 v1 = *(const bf16x8*)(V1b + nb * 512 + lane * 8);
    f32x4 acc = {0.f, 0.f, 0.f, 0.f};
    acc = __builtin_amdgcn_mfma_f32_16x16x32_bf16(ah, v1, acc, 0, 0, 0);
    int col = 16 * nb + q;
    float bias = b1[col];
#pragma unroll
    for (int r = 0; r < 4; ++r) {
      float f = fmaxf(acc[r] + bias, 0.f);
      LF[(4 * g + r) * 136 + col] = (u16)bf16r(f);
    }
  }
  __syncthreads();

  f32x4 a20 = {0.f, 0.f, 0.f, 0.f}, a21 = {0.f, 0.f, 0.f, 0.f};
#pragma unroll
  for (int kb = 0; kb < 4; ++kb) {
    bf16x8 af2 = *(const bf16x8*)(LF + q * 136 + kb * 32 + g * 8);
    bf16x8 v20 = *(const bf16x8*)(V2b + (kb * 2 + 0) * 512 + lane * 8);
    bf16x8 v21 = *(const bf16x8*)(V2b + (kb * 2 + 1) * 512 + lane * 8);
    a20 = __builtin_amdgcn_mfma_f32_16x16x32_bf16(af2, v20, a20, 0, 0, 0);
    a21 = __builtin_amdgcn_mfma_f32_16x16x32_bf16(af2, v21, a21, 0, 0, 0);
  }
  __syncthreads();
#pragma unroll
  for (int r = 0; r < 4; ++r) {
    LO[(4 * g + r) * 36 + q]      = a20[r];
    LO[(4 * g + r) * 36 + 16 + q] = a21[r];
  }
  __syncthreads();

  if (lane < 16) {
    float ov[32];
#pragma unroll
    for (int i = 0; i < 8; ++i) {
      float4 t = *(const float4*)(LO + q * 36 + i * 4);
      ov[4*i] = t.x; ov[4*i+1] = t.y; ov[4*i+2] = t.z; ov[4*i+3] = t.w;
    }
#pragma unroll
    for (int c = 0; c < 32; ++c) ov[c] += b2[c] + hv[c];
    float mu2 = 0.f;
#pragma unroll
    for (int c = 0; c < 32; ++c) mu2 += ov[c];
    mu2 *= (1.f / 32.f);
    float var2 = 0.f;
#pragma unroll
    for (int c = 0; c < 32; ++c) { float t = ov[c] - mu2; var2 = fmaf(t, t, var2); }
    float rs2 = rsqrtf(var2 * (1.f / 32.f) + LNEPS);
    float* op = out + (node0 + q) * CC;
#pragma unroll
    for (int i = 0; i < 8; ++i) {
      float4 o;
      o.x = (ov[4*i]   - mu2) * rs2 * g2[4*i]   + be2[4*i];
      o.y = (ov[4*i+1] - mu2) * rs2 * g2[4*i+1] + be2[4*i+1];
      o.z = (ov[4*i+2] - mu2) * rs2 * g2[4*i+2] + be2[4*i+2];
      o.w = (ov[4*i+3] - mu2) * rs2 * g2[4*i+3] + be2[4*i+3];
      *(float4*)(op + i * 4) = o;
    }
  }
}

// ---------- launch ----------
extern "C" void kernel_launch(void* const* d_in, const int* in_sizes, int n_in,
                              void* d_out, int out_size, void* d_ws, size_t ws_size,
                              hipStream_t stream)
{
  const float* x    = (const float*)d_in[0];
  const int*   ei   = (const int*)d_in[1];
  const float* W    = (const float*)d_in[2];
  const float* atts = (const float*)d_in[3];
  const float* attd = (const float*)d_in[4];
  const float* bg   = (const float*)d_in[5];
  const float* w1   = (const float*)d_in[6];
  const float* b1   = (const float*)d_in[7];
  const float* w2   = (const float*)d_in[8];
  const float* b2   = (const float*)d_in[9];
  const float* g1   = (const float*)d_in[10];
  const float* be1  = (const float*)d_in[11];
  const float* g2   = (const float*)d_in[12];
  const float* be2  = (const float*)d_in[13];

  int n = in_sizes[0] / CC;
  int e = in_sizes[1] / 2;

  uint8_t* ws = (uint8_t*)d_ws;
  size_t o = 0;
  unsigned* xq8 = (unsigned*)(ws + o); o += (size_t)n * 256;   // int8 rows, 256B/node
  unsigned* ascp = (unsigned*)(ws + o); o += (size_t)n * HH * 4; // bf16 a_src|fp16 scale
  float* a_d = (float*)(ws + o); o += (size_t)n * HH * 4;
  float* og  = (float*)(ws + o); o += (size_t)n * CC * 4;
  int* deg    = (int*)(ws + o); o += (size_t)n * 4;
  int* offs   = (int*)(ws + o); o += (size_t)n * 4;
  unsigned* dstr = (unsigned*)(ws + o); o += (size_t)e * 4;
  int* csr    = (int*)(ws + o); o += (size_t)e * 4;
  int* bsum   = (int*)(ws + o); o += 4096;
  u16* Wb  = (u16*)(ws + o); o += 16 * 512 * 2;
  u16* Zb  = (u16*)(ws + o); o += 8 * 512 * 2;
  u16* V1b = (u16*)(ws + o); o += 8 * 512 * 2;
  u16* V2b = (u16*)(ws + o); o += 8 * 512 * 2;

  (void)hipMemsetAsync(deg, 0, (size_t)n * 4, stream);

  int nwaves = (n + 15) / 16;
  int nbc   = (nwaves + 3) / 4;
  int nb_e4 = (e + 1023) / 1024;
  int nb_s  = (n + 1023) / 1024;

  klayout <<<1, 256, 0, stream>>>(W, atts, attd, w1, w2, Wb, Zb, V1b, V2b);
  k1m     <<<nbc + nb_e4, 256, 0, stream>>>(x, Wb, Zb, ei, xq8, ascp, a_d, deg,
                                            dstr, n, e, nbc);
  kscanA  <<<nb_s, 256, 0, stream>>>(deg, bsum, n);
  kscanB  <<<1, 1024, 0, stream>>>(bsum, nb_s);
  kscanC  <<<nb_s, 256, 0, stream>>>(deg, bsum, offs, n);
  kscatter<<<512, 256, 0, stream>>>(ei, dstr, e, offs, csr, n);
  kagg    <<<(n + 3) / 4, 256, 0, stream>>>(csr, offs, deg, ascp, a_d, xq8, og, n);
  k5m     <<<nbc, 256, 0, stream>>>(og, x, bg, V1b, V2b, b1, b2, g1, be1, g2, be2,
                                    (float*)d_out, n);
}